// Round 11
// baseline (986.604 us; speedup 1.0000x reference)
//
#include <hip/hip_runtime.h>
#include <math.h>

#define NN 25000
#define NE 50000
#define NEP2 50176            // 98 * 512 edges (padded)
#define NATOM 26
#define NUM_ITER 3
#define NCH 33                // K' = 33 chunks x 256 (4 k-values x 64 i's)
#define NPB 32
#define EB2 512               // edges per block
#define KSP 17                // chunks per K-split block: [0,17) and [17,33)

typedef __attribute__((ext_vector_type(8))) short bf16x8;
typedef __attribute__((ext_vector_type(8))) unsigned short ushort8_t;
typedef __attribute__((ext_vector_type(4))) float f32x4;
union FragU { bf16x8 v; ushort4 q[2]; };

#define GLDS16(gp, lp) __builtin_amdgcn_global_load_lds( \
    (const __attribute__((address_space(1))) void*)(gp), \
    (__attribute__((address_space(3))) void*)(lp), 16, 0, 0)

static __device__ __forceinline__ ushort f2bf(float f) {
  unsigned u = __float_as_uint(f);
  unsigned r = (u + 0x7FFFu + ((u >> 16) & 1u)) >> 16;
  return (ushort)r;
}
static __device__ __forceinline__ unsigned cvt_pk_bf16(float a, float b) {
  unsigned r;
  asm("v_cvt_pk_bf16_f32 %0, %1, %2" : "=v"(r) : "v"(a), "v"(b));
  return r;
}
static __device__ __forceinline__ float bflo(unsigned u) { return __uint_as_float(u << 16); }
static __device__ __forceinline__ float bfhi(unsigned u) { return __uint_as_float(u & 0xFFFF0000u); }

// ---------------- U pack: relu(ea@We1+be1) -> Upkt[g][e][4] bf16 (k-group-major)
__global__ __launch_bounds__(256) void edge_mlp_pack_kernel(
    const float* __restrict__ ea, const float* __restrict__ We1,
    const float* __restrict__ be1, ushort* __restrict__ Upkt) {
  int t = threadIdx.x;
  int el = t & 63, seg = t >> 6;
  int e = blockIdx.x * 64 + el;       // grid 784 -> e < 50176
  bool valid = (e < NE);
  float a0 = 0.f, a1 = 0.f, a2 = 0.f, a3 = 0.f;
  if (valid) { a0 = ea[e * 4]; a1 = ea[e * 4 + 1]; a2 = ea[e * 4 + 2]; a3 = ea[e * 4 + 3]; }
  #pragma unroll
  for (int q = 0; q < 8; ++q) {
    int g = seg * 8 + q;              // k-group 0..31 (k = 4g..4g+3 < 128)
    ushort out[4];
    #pragma unroll
    for (int kk = 0; kk < 4; ++kk) {
      int k = g * 4 + kk;
      float v = be1[k];
      v = fmaf(a0, We1[k], v);
      v = fmaf(a1, We1[128 + k], v);
      v = fmaf(a2, We1[256 + k], v);
      v = fmaf(a3, We1[384 + k], v);
      out[kk] = valid ? f2bf(fmaxf(v, 0.f)) : (ushort)0;
    }
    *(ushort4*)&Upkt[((size_t)g * NEP2 + e) * 4] = *(ushort4*)out;
  }
  if (seg == 0) {                     // g=32: k=128 -> 1.0 (be2 fold), 129..131 -> 0
    ushort out[4] = {(ushort)(valid ? 0x3F80 : 0), 0, 0, 0};
    *(ushort4*)&Upkt[((size_t)32 * NEP2 + e) * 4] = *(ushort4*)out;
  }
}

// ---------------- B pack: We2ext[f][o] -> per-lane fragment order
__global__ __launch_bounds__(256) void bpk_pack_kernel(
    const float* __restrict__ We2, const float* __restrict__ be2,
    ushort* __restrict__ Bpk) {
  int idx = blockIdx.x * 256 + threadIdx.x;   // 264 blocks -> 67584 = 33*8*4*64
  int lane = idx & 63;
  int nt = (idx >> 6) & 3;
  int ks = (idx >> 8) & 7;
  int c = idx >> 11;
  int l15 = lane & 15, lg = lane >> 4;
  int o = nt * 16 + l15;
  ushort v[8];
  #pragma unroll
  for (int j = 0; j < 8; ++j) {
    int kl = (j < 4) ? (4 * lg + j) : (12 + 4 * lg + j);   // split-halves k-map
    int f = c * 256 + ks * 32 + kl;
    int k = f >> 6, i = f & 63;
    float wv = 0.f;
    if (k < 128) wv = We2[(size_t)k * 4096 + i * 64 + o];
    else if (k == 128) wv = be2[i * 64 + o];
    v[j] = f2bf(wv);
  }
  *(ushort8_t*)(Bpk + (size_t)idx * 8) = *(ushort8_t*)v;
}

// ---------------- GRU/conv weight pack: fragment-linear bf16 in ws
__global__ __launch_bounds__(256) void nw_pack_kernel(
    const float* __restrict__ W_root, const float* __restrict__ W_ih,
    const float* __restrict__ W_hh, ushort* __restrict__ Wr_pk,
    ushort* __restrict__ Bih_pk, ushort* __restrict__ Bhh_pk) {
  int idx = blockIdx.x * 256 + threadIdx.x;   // 14 blocks -> 3584 frags
  if (idx >= 3584) return;
  int lane, nt, ks, kind;
  ushort* dstp;
  if (idx < 512)      { kind = 0; int f = idx;        lane = f & 63; nt = (f >> 6) % 4;  ks = (f >> 6) / 4;  dstp = Wr_pk  + (size_t)f * 8; }
  else if (idx < 2048){ kind = 1; int f = idx - 512;  lane = f & 63; nt = (f >> 6) % 12; ks = (f >> 6) / 12; dstp = Bih_pk + (size_t)f * 8; }
  else                { kind = 2; int f = idx - 2048; lane = f & 63; nt = (f >> 6) % 12; ks = (f >> 6) / 12; dstp = Bhh_pk + (size_t)f * 8; }
  int l15 = lane & 15, lg = lane >> 4;
  int col = nt * 16 + l15;
  ushort v[8];
  #pragma unroll
  for (int j = 0; j < 8; ++j) {
    int kl = (j < 4) ? (4 * lg + j) : (12 + 4 * lg + j);
    int i = ks * 32 + kl;
    float wv;
    if (kind == 0)      wv = W_root[i * 64 + col];
    else if (kind == 1) wv = W_ih[col * 64 + i];
    else                wv = W_hh[col * 64 + i];
    v[j] = f2bf(wv);
  }
  *(ushort8_t*)dstp = *(ushort8_t*)v;
}

// ---------------- fused edge-message GEMM v5: scale-accumulate formulation.
// A-operand = raw bf16 s (loop-invariant regs); t = s @ W2[k-unit]; acc += u * t.
// 512 edges/block, 512 thr (8 waves), wave tile 64 edges (mt=0..3),
// N split in 2 (32 cols/block), K split in 2.  LDS = 32 KB only.
__global__ __launch_bounds__(512, 4) void edge_rgemm5_kernel(
    const ushort* __restrict__ Upkt, const ushort* __restrict__ Bpk,
    const float* __restrict__ hv, const int* __restrict__ src,
    const int* __restrict__ dst, float* __restrict__ agg) {
  __shared__ ushort sB[2][8192];    // 2 x 16KB: [8 ks][128 frag][8]
  int tid = threadIdx.x;            // 0..511
  int lane = tid & 63, w = tid >> 6;  // 8 waves
  int l15 = lane & 15, lg = lane >> 4;
  int e0 = blockIdx.x * EB2;        // 98 edge-blocks
  int c0 = blockIdx.y * KSP;        // 0 or 17
  int c1 = (c0 + KSP < NCH) ? (c0 + KSP) : NCH;
  int nh = blockIdx.z;              // N-half: cols [nh*32, nh*32+32)

  // prologue DMA: chunk c0 B-slice. Wave w stages ks=w (128 frags = 2KB).
  {
    const ushort* bs = Bpk + ((((size_t)c0 * 8 + w) * 4 + nh * 2) * 64) * 8;
    GLDS16(bs + (size_t)lane * 8, &sB[0][(size_t)(w * 128) * 8]);
    GLDS16(bs + (size_t)(64 + lane) * 8, &sB[0][(size_t)(w * 128 + 64) * 8]);
  }

  // s fragments direct global->reg (bf16, raw MFMA A operands; invariant)
  bf16x8 sfr[4][2];
  #pragma unroll
  for (int mt = 0; mt < 4; ++mt) {
    int e = e0 + w * 64 + mt * 16 + l15;
    int es = (e < NE) ? e : (NE - 1);          // clamp; u=0 for padded edges
    const float* hp = hv + (size_t)src[es] * 64;
    #pragma unroll
    for (int p = 0; p < 2; ++p) {
      float4 a = *(const float4*)(hp + p * 32 + 4 * lg);
      float4 b = *(const float4*)(hp + p * 32 + 16 + 4 * lg);
      union { bf16x8 v; unsigned u[4]; } f;
      f.u[0] = cvt_pk_bf16(a.x, a.y);
      f.u[1] = cvt_pk_bf16(a.z, a.w);
      f.u[2] = cvt_pk_bf16(b.x, b.y);
      f.u[3] = cvt_pk_bf16(b.z, b.w);
      sfr[mt][p] = f.v;
    }
  }
  f32x4 kZ = (f32x4){0.f, 0.f, 0.f, 0.f};

  f32x4 acc[4][2];
  #pragma unroll
  for (int mt = 0; mt < 4; ++mt)
    #pragma unroll
    for (int nt = 0; nt < 2; ++nt) acc[mt][nt] = (f32x4){0.f, 0.f, 0.f, 0.f};
  __syncthreads();

  for (int c = c0; c < c1; ++c) {
    int cur = (c - c0) & 1;
    if (c + 1 < c1) {  // DMA next chunk into other buffer; in flight across compute
      const ushort* bs = Bpk + ((((size_t)(c + 1) * 8 + w) * 4 + nh * 2) * 64) * 8;
      GLDS16(bs + (size_t)lane * 8, &sB[cur ^ 1][(size_t)(w * 128) * 8]);
      GLDS16(bs + (size_t)(64 + lane) * 8, &sB[cur ^ 1][(size_t)(w * 128 + 64) * 8]);
    }
    #pragma unroll
    for (int kup = 0; kup < 2; ++kup) {
      // u words for k-units {2kup, 2kup+1}: row-matched to D rows (lg*4+rr)
      unsigned uw[4][4];
      #pragma unroll
      for (int mt = 0; mt < 4; ++mt) {
        const ushort* up = Upkt + ((size_t)c * NEP2 + e0 + w * 64 + mt * 16 + lg * 4) * 4 + kup * 2;
        #pragma unroll
        for (int rr = 0; rr < 4; ++rr)
          uw[mt][rr] = *(const unsigned*)(up + rr * 4);
      }
      #pragma unroll
      for (int kh = 0; kh < 2; ++kh) {
        int ku = kup * 2 + kh;
        bf16x8 b0[2], b1[2];
        #pragma unroll
        for (int nt = 0; nt < 2; ++nt) {
          b0[nt] = *(const bf16x8*)&sB[cur][(((size_t)(2 * ku) * 128) + nt * 64 + lane) * 8];
          b1[nt] = *(const bf16x8*)&sB[cur][(((size_t)(2 * ku + 1) * 128) + nt * 64 + lane) * 8];
        }
        #pragma unroll
        for (int mt = 0; mt < 4; ++mt) {
          float uf[4];
          #pragma unroll
          for (int rr = 0; rr < 4; ++rr)
            uf[rr] = kh ? bfhi(uw[mt][rr]) : bflo(uw[mt][rr]);
          #pragma unroll
          for (int nt = 0; nt < 2; ++nt) {
            f32x4 t = __builtin_amdgcn_mfma_f32_16x16x32_bf16(sfr[mt][0], b0[nt], kZ, 0, 0, 0);
            t = __builtin_amdgcn_mfma_f32_16x16x32_bf16(sfr[mt][1], b1[nt], t, 0, 0, 0);
            #pragma unroll
            for (int rr = 0; rr < 4; ++rr)
              acc[mt][nt][rr] = fmaf(uf[rr], t[rr], acc[mt][nt][rr]);
          }
        }
      }
    }
    __syncthreads();  // drains next-chunk DMA (hidden under compute) + buffer handoff
  }

  // scatter: D row (within 16-tile) = lg*4 + rr, col = nh*32 + nt*16 + l15
  #pragma unroll
  for (int mt = 0; mt < 4; ++mt) {
    #pragma unroll
    for (int rr = 0; rr < 4; ++rr) {
      int e = e0 + w * 64 + mt * 16 + lg * 4 + rr;
      if (e < NE) {
        int d = dst[e];
        #pragma unroll
        for (int nt = 0; nt < 2; ++nt)
          atomicAdd(&agg[(size_t)d * 64 + nh * 32 + nt * 16 + l15], acc[mt][nt][rr]);
      }
    }
  }
}

// ---------------- node input transform
__global__ __launch_bounds__(256) void node_in_kernel(
    const float* __restrict__ x, const float* __restrict__ W_in,
    const float* __restrict__ b_in, float* __restrict__ h) {
  int idx = blockIdx.x * 256 + threadIdx.x;
  if (idx >= NN * 64) return;
  int n = idx >> 6, c = idx & 63;
  float acc = b_in[c];
  #pragma unroll
  for (int j = 0; j < NATOM; ++j) acc = fmaf(x[n * NATOM + j], W_in[j * 64 + c], acc);
  h[idx] = fmaxf(acc, 0.f);
}

// ---------------- node update v2: MFMA GRU. 128 nodes/block, 256 thr (4 waves x 32 nodes)
__global__ __launch_bounds__(256, 1) void node_update2_kernel(
    float* __restrict__ hv, const float* __restrict__ agg,
    const ushort* __restrict__ Wr_pk, const ushort* __restrict__ Bih_pk,
    const ushort* __restrict__ Bhh_pk, const float* __restrict__ b_conv,
    const float* __restrict__ b_ih, const float* __restrict__ b_hh) {
  __shared__ ushort h_lds[128][72];   // 18 KB
  __shared__ ushort m_lds[128][72];   // 18 KB
  int tid = threadIdx.x;
  int lane = tid & 63, w = tid >> 6;
  int l15 = lane & 15, lg = lane >> 4;
  int n0 = blockIdx.x * 128;

  #pragma unroll
  for (int r = 0; r < 8; ++r) {
    int idx = r * 256 + tid;
    int row = idx >> 4, part = idx & 15;
    int n = n0 + row;
    float4 v = make_float4(0.f, 0.f, 0.f, 0.f);
    if (n < NN) v = ((const float4*)hv)[(size_t)n * 16 + part];
    *(uint2*)&h_lds[row][part * 4] =
        make_uint2(cvt_pk_bf16(v.x, v.y), cvt_pk_bf16(v.z, v.w));
  }
  __syncthreads();

  bf16x8 ah[2][2];
  #pragma unroll
  for (int mt = 0; mt < 2; ++mt)
    #pragma unroll
    for (int ks = 0; ks < 2; ++ks) {
      int row = w * 32 + mt * 16 + l15;
      FragU f;
      f.q[0] = *(const ushort4*)&h_lds[row][ks * 32 + 4 * lg];
      f.q[1] = *(const ushort4*)&h_lds[row][ks * 32 + 16 + 4 * lg];
      ah[mt][ks] = f.v;
    }

  f32x4 accm[2][4];
  #pragma unroll
  for (int mt = 0; mt < 2; ++mt)
    #pragma unroll
    for (int nt = 0; nt < 4; ++nt) accm[mt][nt] = (f32x4){0.f, 0.f, 0.f, 0.f};
  #pragma unroll
  for (int ks = 0; ks < 2; ++ks)
    #pragma unroll
    for (int nt = 0; nt < 4; ++nt) {
      bf16x8 b = *(const bf16x8*)(Wr_pk + ((size_t)((ks * 4 + nt) * 64 + lane)) * 8);
      #pragma unroll
      for (int mt = 0; mt < 2; ++mt)
        accm[mt][nt] = __builtin_amdgcn_mfma_f32_16x16x32_bf16(ah[mt][ks], b, accm[mt][nt], 0, 0, 0);
    }
  #pragma unroll
  for (int mt = 0; mt < 2; ++mt)
    #pragma unroll
    for (int nt = 0; nt < 4; ++nt) {
      int col = nt * 16 + l15;
      float bc = b_conv[col];
      #pragma unroll
      for (int rr = 0; rr < 4; ++rr) {
        int row = w * 32 + mt * 16 + lg * 4 + rr;
        int n = n0 + row;
        float val = 0.f;
        if (n < NN) val = fmaxf(accm[mt][nt][rr] + agg[(size_t)n * 64 + col] + bc, 0.f);
        m_lds[row][col] = f2bf(val);
      }
    }
  __syncthreads();

  bf16x8 am[2][2];
  #pragma unroll
  for (int mt = 0; mt < 2; ++mt)
    #pragma unroll
    for (int ks = 0; ks < 2; ++ks) {
      int row = w * 32 + mt * 16 + l15;
      FragU f;
      f.q[0] = *(const ushort4*)&m_lds[row][ks * 32 + 4 * lg];
      f.q[1] = *(const ushort4*)&m_lds[row][ks * 32 + 16 + 4 * lg];
      am[mt][ks] = f.v;
    }

  f32x4 acc_s[2][8], acc_in[2][4], acc_hn[2][4];
  #pragma unroll
  for (int mt = 0; mt < 2; ++mt) {
    #pragma unroll
    for (int nt = 0; nt < 8; ++nt) acc_s[mt][nt] = (f32x4){0.f, 0.f, 0.f, 0.f};
    #pragma unroll
    for (int nt = 0; nt < 4; ++nt) {
      acc_in[mt][nt] = (f32x4){0.f, 0.f, 0.f, 0.f};
      acc_hn[mt][nt] = (f32x4){0.f, 0.f, 0.f, 0.f};
    }
  }
  #pragma unroll
  for (int ks = 0; ks < 2; ++ks) {
    #pragma unroll
    for (int nt = 0; nt < 8; ++nt) {
      bf16x8 bi = *(const bf16x8*)(Bih_pk + ((size_t)((ks * 12 + nt) * 64 + lane)) * 8);
      bf16x8 bh = *(const bf16x8*)(Bhh_pk + ((size_t)((ks * 12 + nt) * 64 + lane)) * 8);
      #pragma unroll
      for (int mt = 0; mt < 2; ++mt) {
        acc_s[mt][nt] = __builtin_amdgcn_mfma_f32_16x16x32_bf16(am[mt][ks], bi, acc_s[mt][nt], 0, 0, 0);
        acc_s[mt][nt] = __builtin_amdgcn_mfma_f32_16x16x32_bf16(ah[mt][ks], bh, acc_s[mt][nt], 0, 0, 0);
      }
    }
    #pragma unroll
    for (int nt = 8; nt < 12; ++nt) {
      bf16x8 bi = *(const bf16x8*)(Bih_pk + ((size_t)((ks * 12 + nt) * 64 + lane)) * 8);
      bf16x8 bh = *(const bf16x8*)(Bhh_pk + ((size_t)((ks * 12 + nt) * 64 + lane)) * 8);
      #pragma unroll
      for (int mt = 0; mt < 2; ++mt) {
        acc_in[mt][nt - 8] = __builtin_amdgcn_mfma_f32_16x16x32_bf16(am[mt][ks], bi, acc_in[mt][nt - 8], 0, 0, 0);
        acc_hn[mt][nt - 8] = __builtin_amdgcn_mfma_f32_16x16x32_bf16(ah[mt][ks], bh, acc_hn[mt][nt - 8], 0, 0, 0);
      }
    }
  }

  #pragma unroll
  for (int mt = 0; mt < 2; ++mt)
    #pragma unroll
    for (int nt = 0; nt < 4; ++nt) {
      int col = nt * 16 + l15;
      float b_sr = b_ih[col] + b_hh[col];
      float b_sz = b_ih[64 + col] + b_hh[64 + col];
      float b_in_ = b_ih[128 + col];
      float b_hn = b_hh[128 + col];
      #pragma unroll
      for (int rr = 0; rr < 4; ++rr) {
        int row = w * 32 + mt * 16 + lg * 4 + rr;
        int n = n0 + row;
        if (n >= NN) continue;
        float Sr = acc_s[mt][nt][rr] + b_sr;
        float Sz = acc_s[mt][nt + 4][rr] + b_sz;
        float vin = acc_in[mt][nt][rr] + b_in_;
        float vhn = acc_hn[mt][nt][rr] + b_hn;
        float r = 1.f / (1.f + __expf(-Sr));
        float z = 1.f / (1.f + __expf(-Sz));
        float nn = tanhf(fmaf(r, vhn, vin));
        float hp = hv[(size_t)n * 64 + col];
        hv[(size_t)n * 64 + col] = (1.f - z) * nn + z * hp;
      }
    }
}

// ---------------- head v3: feat only (NO atomics)
__global__ __launch_bounds__(256) void head2_kernel(
    const float* __restrict__ hv, const float* __restrict__ x,
    const float* __restrict__ Wo1, const float* __restrict__ bo1,
    const float* __restrict__ Wo2, const float* __restrict__ bo2,
    float* __restrict__ feat) {
  __shared__ float wo1[64 * 64];
  __shared__ float wo2[64 * 64];
  __shared__ float s_row[NPB * 64];
  __shared__ float s_o1[NPB * 64];
  int tid = threadIdx.x;
  int n0 = blockIdx.x * NPB;

  for (int idx = tid; idx < 64 * 16; idx += 256) {
    ((float4*)wo1)[idx] = ((const float4*)Wo1)[idx];
    ((float4*)wo2)[idx] = ((const float4*)Wo2)[idx];
  }
  for (int idx = tid; idx < NPB * 64; idx += 256) {
    int n = n0 + (idx >> 6);
    s_row[idx] = (n < NN) ? hv[(size_t)n * 64 + (idx & 63)] : 0.f;
  }
  __syncthreads();

  int c = tid & 63, g = tid >> 6;
  #pragma unroll
  for (int q = 0; q < 8; ++q) {
    int nl = g + 4 * q;
    float a = bo1[c];
    for (int i = 0; i < 64; ++i) a = fmaf(s_row[nl * 64 + i], wo1[i * 64 + c], a);
    s_o1[nl * 64 + c] = fmaxf(a, 0.f);
  }
  __syncthreads();
  #pragma unroll
  for (int q = 0; q < 8; ++q) {
    int nl = g + 4 * q;
    int n = n0 + nl;
    float b = bo2[c];
    for (int i = 0; i < 64; ++i) b = fmaf(s_o1[nl * 64 + i], wo2[i * 64 + c], b);
    float xv = (c < NATOM && n < NN) ? x[(size_t)n * NATOM + c] : 0.f;
    float sq = b * b + xv * xv;
    #pragma unroll
    for (int off = 1; off < 64; off <<= 1) sq += __shfl_xor(sq, off);
    if (n >= NN) continue;
    float inv = 1.f / fmaxf(sqrtf(sq), 1e-12f);
    feat[(size_t)n * 90 + c] = b * inv;
    if (c < NATOM) feat[(size_t)n * 90 + 64 + c] = xv * inv;
  }
}

// ---------------- readout: segment mean prep via binary search (no atomics)
static __device__ __forceinline__ int lbound(const int* __restrict__ b, int v) {
  int lo = 0, hi = NN;
  while (lo < hi) { int m = (lo + hi) >> 1; if (b[m] < v) lo = m + 1; else hi = m; }
  return lo;
}

__global__ __launch_bounds__(128) void readout_kernel(
    const float* __restrict__ feat, const int* __restrict__ batch,
    float* __restrict__ readout, float* __restrict__ cnt) {
  __shared__ int bounds[2];
  int g = blockIdx.x;                // 0..63
  int t = threadIdx.x;
  if (t == 0) bounds[0] = lbound(batch, g);
  if (t == 1) bounds[1] = lbound(batch, g + 1);
  __syncthreads();
  int lo = bounds[0], hi = bounds[1];
  if (t < 90) {
    float a0 = 0.f, a1 = 0.f, a2 = 0.f, a3 = 0.f;
    int n = lo;
    for (; n + 3 < hi; n += 4) {
      a0 += feat[(size_t)n * 90 + t];
      a1 += feat[(size_t)(n + 1) * 90 + t];
      a2 += feat[(size_t)(n + 2) * 90 + t];
      a3 += feat[(size_t)(n + 3) * 90 + t];
    }
    for (; n < hi; ++n) a0 += feat[(size_t)n * 90 + t];
    readout[g * 90 + t] = (a0 + a1) + (a2 + a3);
  }
  if (t == 0) cnt[g] = (float)(hi - lo);
}

__global__ __launch_bounds__(64) void ratio_kernel(
    const float* __restrict__ readout, const float* __restrict__ cnt,
    const float* __restrict__ Wp, const float* __restrict__ bp,
    float* __restrict__ ratio) {
  int g = threadIdx.x;
  float c = fmaxf(cnt[g], 1.f);
  float a = bp[0];
  for (int j = 0; j < 90; ++j) a = fmaf(readout[g * 90 + j] / c, Wp[j], a);
  ratio[g] = 1.f / (1.f + __expf(-a));
}

// ==================== launcher ====================

extern "C" void kernel_launch(void* const* d_in, const int* in_sizes, int n_in,
                              void* d_out, int out_size, void* d_ws, size_t ws_size,
                              hipStream_t stream) {
  const float* x      = (const float*)d_in[0];
  const int*   ei     = (const int*)  d_in[1];
  const float* ea     = (const float*)d_in[2];
  const int*   batch  = (const int*)  d_in[3];
  const float* W_in   = (const float*)d_in[4];
  const float* b_in   = (const float*)d_in[5];
  const float* We1    = (const float*)d_in[6];
  const float* be1    = (const float*)d_in[7];
  const float* We2    = (const float*)d_in[8];
  const float* be2    = (const float*)d_in[9];
  const float* W_root = (const float*)d_in[10];
  const float* b_conv = (const float*)d_in[11];
  const float* W_ih   = (const float*)d_in[12];
  const float* b_ih   = (const float*)d_in[13];
  const float* W_hh   = (const float*)d_in[14];
  const float* b_hh   = (const float*)d_in[15];
  const float* Wo1    = (const float*)d_in[16];
  const float* bo1    = (const float*)d_in[17];
  const float* Wo2    = (const float*)d_in[18];
  const float* bo2    = (const float*)d_in[19];
  const float* Wp     = (const float*)d_in[20];
  const float* bp     = (const float*)d_in[21];

  const int* srcp = ei;
  const int* dstp = ei + NE;
  float* feat  = (float*)d_out;
  float* ratio = feat + (size_t)NN * 90;

  // ws layout (bytes): total ~27.2 MB (round-1 proved >= 39.3 MB available)
  char* wsb = (char*)d_ws;
  ushort* Upkt   = (ushort*)(wsb + 0);            // 13,246,464
  ushort* Bpk    = (ushort*)(wsb + 13246464);     //  1,081,344
  float*  h      = (float*) (wsb + 14327808);     //  6,400,000
  float*  agg    = (float*) (wsb + 20727808);     //  6,400,000
  float*  readout= (float*) (wsb + 27127808);     //     23,040
  float*  cnt    = (float*) (wsb + 27150848);     //        256
  ushort* Wr_pk  = (ushort*)(wsb + 27151104);     //      8,192
  ushort* Bih_pk = (ushort*)(wsb + 27159296);     //     24,576
  ushort* Bhh_pk = (ushort*)(wsb + 27183872);     //     24,576  -> 27,208,448 total

  edge_mlp_pack_kernel<<<NEP2 / 64, 256, 0, stream>>>(ea, We1, be1, Upkt);
  bpk_pack_kernel<<<(NCH * 8 * 4 * 64) / 256, 256, 0, stream>>>(We2, be2, Bpk);
  nw_pack_kernel<<<14, 256, 0, stream>>>(W_root, W_ih, W_hh, Wr_pk, Bih_pk, Bhh_pk);
  node_in_kernel<<<(NN * 64 + 255) / 256, 256, 0, stream>>>(x, W_in, b_in, h);

  for (int it = 0; it < NUM_ITER; ++it) {
    hipMemsetAsync(agg, 0, (size_t)NN * 64 * sizeof(float), stream);
    edge_rgemm5_kernel<<<dim3(NEP2 / EB2, 2, 2), 512, 0, stream>>>(
        Upkt, Bpk, h, srcp, dstp, agg);
    node_update2_kernel<<<(NN + 127) / 128, 256, 0, stream>>>(
        h, agg, Wr_pk, Bih_pk, Bhh_pk, b_conv, b_ih, b_hh);
  }

  head2_kernel<<<(NN + NPB - 1) / NPB, 256, 0, stream>>>(
      h, x, Wo1, bo1, Wo2, bo2, feat);
  readout_kernel<<<64, 128, 0, stream>>>(feat, batch, readout, cnt);
  ratio_kernel<<<1, 64, 0, stream>>>(readout, cnt, Wp, bp, ratio);
}

// Round 12
// 469.301 us; speedup vs baseline: 2.1023x; 2.1023x over previous
//
#include <hip/hip_runtime.h>
#include <math.h>

#define NN 25000
#define NE 50000
#define NEP2 50176            // 98 * 512 edges (padded)
#define NATOM 26
#define NUM_ITER 3
#define NCH 33                // K' = 33 chunks x 256 (4 k-values x 64 i's)
#define NPB 32
#define EB2 512               // edges per block
#define KSP 17                // chunks per K-split block: [0,17) and [17,33)

typedef __attribute__((ext_vector_type(8))) short bf16x8;
typedef __attribute__((ext_vector_type(8))) unsigned short ushort8_t;
typedef __attribute__((ext_vector_type(4))) float f32x4;
union FragU { bf16x8 v; ushort4 q[2]; };

#define GLDS16(gp, lp) __builtin_amdgcn_global_load_lds( \
    (const __attribute__((address_space(1))) void*)(gp), \
    (__attribute__((address_space(3))) void*)(lp), 16, 0, 0)

static __device__ __forceinline__ ushort f2bf(float f) {
  unsigned u = __float_as_uint(f);
  unsigned r = (u + 0x7FFFu + ((u >> 16) & 1u)) >> 16;
  return (ushort)r;
}
static __device__ __forceinline__ unsigned cvt_pk_bf16(float a, float b) {
  unsigned r;
  asm("v_cvt_pk_bf16_f32 %0, %1, %2" : "=v"(r) : "v"(a), "v"(b));
  return r;
}
static __device__ __forceinline__ float bflo(unsigned u) { return __uint_as_float(u << 16); }
static __device__ __forceinline__ float bfhi(unsigned u) { return __uint_as_float(u & 0xFFFF0000u); }

// ---------------- U pack: relu(ea@We1+be1) -> Upkt[g][e][4] bf16 (k-group-major)
__global__ __launch_bounds__(256) void edge_mlp_pack_kernel(
    const float* __restrict__ ea, const float* __restrict__ We1,
    const float* __restrict__ be1, ushort* __restrict__ Upkt) {
  int t = threadIdx.x;
  int el = t & 63, seg = t >> 6;
  int e = blockIdx.x * 64 + el;       // grid 784 -> e < 50176
  bool valid = (e < NE);
  float a0 = 0.f, a1 = 0.f, a2 = 0.f, a3 = 0.f;
  if (valid) { a0 = ea[e * 4]; a1 = ea[e * 4 + 1]; a2 = ea[e * 4 + 2]; a3 = ea[e * 4 + 3]; }
  #pragma unroll
  for (int q = 0; q < 8; ++q) {
    int g = seg * 8 + q;              // k-group 0..31 (k = 4g..4g+3 < 128)
    ushort out[4];
    #pragma unroll
    for (int kk = 0; kk < 4; ++kk) {
      int k = g * 4 + kk;
      float v = be1[k];
      v = fmaf(a0, We1[k], v);
      v = fmaf(a1, We1[128 + k], v);
      v = fmaf(a2, We1[256 + k], v);
      v = fmaf(a3, We1[384 + k], v);
      out[kk] = valid ? f2bf(fmaxf(v, 0.f)) : (ushort)0;
    }
    *(ushort4*)&Upkt[((size_t)g * NEP2 + e) * 4] = *(ushort4*)out;
  }
  if (seg == 0) {                     // g=32: k=128 -> 1.0 (be2 fold), 129..131 -> 0
    ushort out[4] = {(ushort)(valid ? 0x3F80 : 0), 0, 0, 0};
    *(ushort4*)&Upkt[((size_t)32 * NEP2 + e) * 4] = *(ushort4*)out;
  }
}

// ---------------- B pack: We2ext[f][o] -> per-lane fragment order
__global__ __launch_bounds__(256) void bpk_pack_kernel(
    const float* __restrict__ We2, const float* __restrict__ be2,
    ushort* __restrict__ Bpk) {
  int idx = blockIdx.x * 256 + threadIdx.x;   // 264 blocks -> 67584 = 33*8*4*64
  int lane = idx & 63;
  int nt = (idx >> 6) & 3;
  int ks = (idx >> 8) & 7;
  int c = idx >> 11;
  int l15 = lane & 15, lg = lane >> 4;
  int o = nt * 16 + l15;
  ushort v[8];
  #pragma unroll
  for (int j = 0; j < 8; ++j) {
    int kl = (j < 4) ? (4 * lg + j) : (12 + 4 * lg + j);   // split-halves k-map
    int f = c * 256 + ks * 32 + kl;
    int k = f >> 6, i = f & 63;
    float wv = 0.f;
    if (k < 128) wv = We2[(size_t)k * 4096 + i * 64 + o];
    else if (k == 128) wv = be2[i * 64 + o];
    v[j] = f2bf(wv);
  }
  *(ushort8_t*)(Bpk + (size_t)idx * 8) = *(ushort8_t*)v;
}

// ---------------- GRU/conv weight pack: fragment-linear bf16 in ws
__global__ __launch_bounds__(256) void nw_pack_kernel(
    const float* __restrict__ W_root, const float* __restrict__ W_ih,
    const float* __restrict__ W_hh, ushort* __restrict__ Wr_pk,
    ushort* __restrict__ Bih_pk, ushort* __restrict__ Bhh_pk) {
  int idx = blockIdx.x * 256 + threadIdx.x;   // 14 blocks -> 3584 frags
  if (idx >= 3584) return;
  int lane, nt, ks, kind;
  ushort* dstp;
  if (idx < 512)      { kind = 0; int f = idx;        lane = f & 63; nt = (f >> 6) % 4;  ks = (f >> 6) / 4;  dstp = Wr_pk  + (size_t)f * 8; }
  else if (idx < 2048){ kind = 1; int f = idx - 512;  lane = f & 63; nt = (f >> 6) % 12; ks = (f >> 6) / 12; dstp = Bih_pk + (size_t)f * 8; }
  else                { kind = 2; int f = idx - 2048; lane = f & 63; nt = (f >> 6) % 12; ks = (f >> 6) / 12; dstp = Bhh_pk + (size_t)f * 8; }
  int l15 = lane & 15, lg = lane >> 4;
  int col = nt * 16 + l15;
  ushort v[8];
  #pragma unroll
  for (int j = 0; j < 8; ++j) {
    int kl = (j < 4) ? (4 * lg + j) : (12 + 4 * lg + j);
    int i = ks * 32 + kl;
    float wv;
    if (kind == 0)      wv = W_root[i * 64 + col];
    else if (kind == 1) wv = W_ih[col * 64 + i];
    else                wv = W_hh[col * 64 + i];
    v[j] = f2bf(wv);
  }
  *(ushort8_t*)dstp = *(ushort8_t*)v;
}

// ---------------- fused edge-message GEMM v6: scale-accumulate (v5 math, verified),
// spill-free tiling. 512 edges/block, 1024 thr (16 waves), wave tile 32 edges
// (mt=0..1), N split in 2 (32 cols), K split in 2. LDS = 32 KB.
__global__ __launch_bounds__(1024, 2) void edge_rgemm6_kernel(
    const ushort* __restrict__ Upkt, const ushort* __restrict__ Bpk,
    const float* __restrict__ hv, const int* __restrict__ src,
    const int* __restrict__ dst, float* __restrict__ agg) {
  __shared__ ushort sB[2][8192];    // 2 x 16KB: [8 ks][2 nt][64 lane][8]
  int tid = threadIdx.x;            // 0..1023
  int lane = tid & 63, w = tid >> 6;  // 16 waves
  int l15 = lane & 15, lg = lane >> 4;
  int e0 = blockIdx.x * EB2;        // 98 edge-blocks
  int c0 = blockIdx.y * KSP;        // 0 or 17
  int c1 = (c0 + KSP < NCH) ? (c0 + KSP) : NCH;
  int nh = blockIdx.z;              // N-half: cols [nh*32, nh*32+32)

  // prologue DMA: chunk c0 B-slice. Wave w stages (ks=w>>1, nt=w&1): 1KB.
  {
    const ushort* bs = Bpk + ((((size_t)c0 * 8 + (w >> 1)) * 4 + nh * 2 + (w & 1)) * 64) * 8;
    GLDS16(bs + (size_t)lane * 8, &sB[0][(size_t)(w * 64) * 8]);
  }

  // s fragments direct global->reg (bf16, raw MFMA A operands; loop-invariant)
  bf16x8 sfr[2][2];
  #pragma unroll
  for (int mt = 0; mt < 2; ++mt) {
    int e = e0 + w * 32 + mt * 16 + l15;
    int es = (e < NE) ? e : (NE - 1);          // clamp; u=0 for padded edges
    const float* hp = hv + (size_t)src[es] * 64;
    #pragma unroll
    for (int p = 0; p < 2; ++p) {
      float4 a = *(const float4*)(hp + p * 32 + 4 * lg);
      float4 b = *(const float4*)(hp + p * 32 + 16 + 4 * lg);
      union { bf16x8 v; unsigned u[4]; } f;
      f.u[0] = cvt_pk_bf16(a.x, a.y);
      f.u[1] = cvt_pk_bf16(a.z, a.w);
      f.u[2] = cvt_pk_bf16(b.x, b.y);
      f.u[3] = cvt_pk_bf16(b.z, b.w);
      sfr[mt][p] = f.v;
    }
  }
  f32x4 kZ = (f32x4){0.f, 0.f, 0.f, 0.f};

  f32x4 acc[2][2];
  #pragma unroll
  for (int mt = 0; mt < 2; ++mt)
    #pragma unroll
    for (int nt = 0; nt < 2; ++nt) acc[mt][nt] = (f32x4){0.f, 0.f, 0.f, 0.f};
  __syncthreads();

  for (int c = c0; c < c1; ++c) {
    int cur = (c - c0) & 1;
    if (c + 1 < c1) {  // DMA next chunk into other buffer; in flight across compute
      const ushort* bs = Bpk + ((((size_t)(c + 1) * 8 + (w >> 1)) * 4 + nh * 2 + (w & 1)) * 64) * 8;
      GLDS16(bs + (size_t)lane * 8, &sB[cur ^ 1][(size_t)(w * 64) * 8]);
    }
    #pragma unroll
    for (int kup = 0; kup < 2; ++kup) {
      // u words for k-units {2kup, 2kup+1}: row-matched to D rows (lg*4+rr)
      unsigned uw[2][4];
      #pragma unroll
      for (int mt = 0; mt < 2; ++mt) {
        const ushort* up = Upkt + ((size_t)c * NEP2 + e0 + w * 32 + mt * 16 + lg * 4) * 4 + kup * 2;
        #pragma unroll
        for (int rr = 0; rr < 4; ++rr)
          uw[mt][rr] = *(const unsigned*)(up + rr * 4);
      }
      #pragma unroll
      for (int kh = 0; kh < 2; ++kh) {
        int ku = kup * 2 + kh;
        bf16x8 b0[2], b1[2];
        #pragma unroll
        for (int nt = 0; nt < 2; ++nt) {
          b0[nt] = *(const bf16x8*)&sB[cur][(((size_t)(2 * ku) * 128) + nt * 64 + lane) * 8];
          b1[nt] = *(const bf16x8*)&sB[cur][(((size_t)(2 * ku + 1) * 128) + nt * 64 + lane) * 8];
        }
        #pragma unroll
        for (int mt = 0; mt < 2; ++mt) {
          float uf[4];
          #pragma unroll
          for (int rr = 0; rr < 4; ++rr)
            uf[rr] = kh ? bfhi(uw[mt][rr]) : bflo(uw[mt][rr]);
          #pragma unroll
          for (int nt = 0; nt < 2; ++nt) {
            f32x4 t = __builtin_amdgcn_mfma_f32_16x16x32_bf16(sfr[mt][0], b0[nt], kZ, 0, 0, 0);
            t = __builtin_amdgcn_mfma_f32_16x16x32_bf16(sfr[mt][1], b1[nt], t, 0, 0, 0);
            #pragma unroll
            for (int rr = 0; rr < 4; ++rr)
              acc[mt][nt][rr] = fmaf(uf[rr], t[rr], acc[mt][nt][rr]);
          }
        }
      }
    }
    __syncthreads();  // drains next-chunk DMA (hidden under compute) + buffer handoff
  }

  // scatter: D row (within 16-tile) = lg*4 + rr, col = nh*32 + nt*16 + l15
  #pragma unroll
  for (int mt = 0; mt < 2; ++mt) {
    #pragma unroll
    for (int rr = 0; rr < 4; ++rr) {
      int e = e0 + w * 32 + mt * 16 + lg * 4 + rr;
      if (e < NE) {
        int d = dst[e];
        #pragma unroll
        for (int nt = 0; nt < 2; ++nt)
          atomicAdd(&agg[(size_t)d * 64 + nh * 32 + nt * 16 + l15], acc[mt][nt][rr]);
      }
    }
  }
}

// ---------------- node input transform
__global__ __launch_bounds__(256) void node_in_kernel(
    const float* __restrict__ x, const float* __restrict__ W_in,
    const float* __restrict__ b_in, float* __restrict__ h) {
  int idx = blockIdx.x * 256 + threadIdx.x;
  if (idx >= NN * 64) return;
  int n = idx >> 6, c = idx & 63;
  float acc = b_in[c];
  #pragma unroll
  for (int j = 0; j < NATOM; ++j) acc = fmaf(x[n * NATOM + j], W_in[j * 64 + c], acc);
  h[idx] = fmaxf(acc, 0.f);
}

// ---------------- node update v2: MFMA GRU. 128 nodes/block, 256 thr (4 waves x 32 nodes)
__global__ __launch_bounds__(256, 1) void node_update2_kernel(
    float* __restrict__ hv, const float* __restrict__ agg,
    const ushort* __restrict__ Wr_pk, const ushort* __restrict__ Bih_pk,
    const ushort* __restrict__ Bhh_pk, const float* __restrict__ b_conv,
    const float* __restrict__ b_ih, const float* __restrict__ b_hh) {
  __shared__ ushort h_lds[128][72];   // 18 KB
  __shared__ ushort m_lds[128][72];   // 18 KB
  int tid = threadIdx.x;
  int lane = tid & 63, w = tid >> 6;
  int l15 = lane & 15, lg = lane >> 4;
  int n0 = blockIdx.x * 128;

  #pragma unroll
  for (int r = 0; r < 8; ++r) {
    int idx = r * 256 + tid;
    int row = idx >> 4, part = idx & 15;
    int n = n0 + row;
    float4 v = make_float4(0.f, 0.f, 0.f, 0.f);
    if (n < NN) v = ((const float4*)hv)[(size_t)n * 16 + part];
    *(uint2*)&h_lds[row][part * 4] =
        make_uint2(cvt_pk_bf16(v.x, v.y), cvt_pk_bf16(v.z, v.w));
  }
  __syncthreads();

  bf16x8 ah[2][2];
  #pragma unroll
  for (int mt = 0; mt < 2; ++mt)
    #pragma unroll
    for (int ks = 0; ks < 2; ++ks) {
      int row = w * 32 + mt * 16 + l15;
      FragU f;
      f.q[0] = *(const ushort4*)&h_lds[row][ks * 32 + 4 * lg];
      f.q[1] = *(const ushort4*)&h_lds[row][ks * 32 + 16 + 4 * lg];
      ah[mt][ks] = f.v;
    }

  f32x4 accm[2][4];
  #pragma unroll
  for (int mt = 0; mt < 2; ++mt)
    #pragma unroll
    for (int nt = 0; nt < 4; ++nt) accm[mt][nt] = (f32x4){0.f, 0.f, 0.f, 0.f};
  #pragma unroll
  for (int ks = 0; ks < 2; ++ks)
    #pragma unroll
    for (int nt = 0; nt < 4; ++nt) {
      bf16x8 b = *(const bf16x8*)(Wr_pk + ((size_t)((ks * 4 + nt) * 64 + lane)) * 8);
      #pragma unroll
      for (int mt = 0; mt < 2; ++mt)
        accm[mt][nt] = __builtin_amdgcn_mfma_f32_16x16x32_bf16(ah[mt][ks], b, accm[mt][nt], 0, 0, 0);
    }
  #pragma unroll
  for (int mt = 0; mt < 2; ++mt)
    #pragma unroll
    for (int nt = 0; nt < 4; ++nt) {
      int col = nt * 16 + l15;
      float bc = b_conv[col];
      #pragma unroll
      for (int rr = 0; rr < 4; ++rr) {
        int row = w * 32 + mt * 16 + lg * 4 + rr;
        int n = n0 + row;
        float val = 0.f;
        if (n < NN) val = fmaxf(accm[mt][nt][rr] + agg[(size_t)n * 64 + col] + bc, 0.f);
        m_lds[row][col] = f2bf(val);
      }
    }
  __syncthreads();

  bf16x8 am[2][2];
  #pragma unroll
  for (int mt = 0; mt < 2; ++mt)
    #pragma unroll
    for (int ks = 0; ks < 2; ++ks) {
      int row = w * 32 + mt * 16 + l15;
      FragU f;
      f.q[0] = *(const ushort4*)&m_lds[row][ks * 32 + 4 * lg];
      f.q[1] = *(const ushort4*)&m_lds[row][ks * 32 + 16 + 4 * lg];
      am[mt][ks] = f.v;
    }

  f32x4 acc_s[2][8], acc_in[2][4], acc_hn[2][4];
  #pragma unroll
  for (int mt = 0; mt < 2; ++mt) {
    #pragma unroll
    for (int nt = 0; nt < 8; ++nt) acc_s[mt][nt] = (f32x4){0.f, 0.f, 0.f, 0.f};
    #pragma unroll
    for (int nt = 0; nt < 4; ++nt) {
      acc_in[mt][nt] = (f32x4){0.f, 0.f, 0.f, 0.f};
      acc_hn[mt][nt] = (f32x4){0.f, 0.f, 0.f, 0.f};
    }
  }
  #pragma unroll
  for (int ks = 0; ks < 2; ++ks) {
    #pragma unroll
    for (int nt = 0; nt < 8; ++nt) {
      bf16x8 bi = *(const bf16x8*)(Bih_pk + ((size_t)((ks * 12 + nt) * 64 + lane)) * 8);
      bf16x8 bh = *(const bf16x8*)(Bhh_pk + ((size_t)((ks * 12 + nt) * 64 + lane)) * 8);
      #pragma unroll
      for (int mt = 0; mt < 2; ++mt) {
        acc_s[mt][nt] = __builtin_amdgcn_mfma_f32_16x16x32_bf16(am[mt][ks], bi, acc_s[mt][nt], 0, 0, 0);
        acc_s[mt][nt] = __builtin_amdgcn_mfma_f32_16x16x32_bf16(ah[mt][ks], bh, acc_s[mt][nt], 0, 0, 0);
      }
    }
    #pragma unroll
    for (int nt = 8; nt < 12; ++nt) {
      bf16x8 bi = *(const bf16x8*)(Bih_pk + ((size_t)((ks * 12 + nt) * 64 + lane)) * 8);
      bf16x8 bh = *(const bf16x8*)(Bhh_pk + ((size_t)((ks * 12 + nt) * 64 + lane)) * 8);
      #pragma unroll
      for (int mt = 0; mt < 2; ++mt) {
        acc_in[mt][nt - 8] = __builtin_amdgcn_mfma_f32_16x16x32_bf16(am[mt][ks], bi, acc_in[mt][nt - 8], 0, 0, 0);
        acc_hn[mt][nt - 8] = __builtin_amdgcn_mfma_f32_16x16x32_bf16(ah[mt][ks], bh, acc_hn[mt][nt - 8], 0, 0, 0);
      }
    }
  }

  #pragma unroll
  for (int mt = 0; mt < 2; ++mt)
    #pragma unroll
    for (int nt = 0; nt < 4; ++nt) {
      int col = nt * 16 + l15;
      float b_sr = b_ih[col] + b_hh[col];
      float b_sz = b_ih[64 + col] + b_hh[64 + col];
      float b_in_ = b_ih[128 + col];
      float b_hn = b_hh[128 + col];
      #pragma unroll
      for (int rr = 0; rr < 4; ++rr) {
        int row = w * 32 + mt * 16 + lg * 4 + rr;
        int n = n0 + row;
        if (n >= NN) continue;
        float Sr = acc_s[mt][nt][rr] + b_sr;
        float Sz = acc_s[mt][nt + 4][rr] + b_sz;
        float vin = acc_in[mt][nt][rr] + b_in_;
        float vhn = acc_hn[mt][nt][rr] + b_hn;
        float r = 1.f / (1.f + __expf(-Sr));
        float z = 1.f / (1.f + __expf(-Sz));
        float nn = tanhf(fmaf(r, vhn, vin));
        float hp = hv[(size_t)n * 64 + col];
        hv[(size_t)n * 64 + col] = (1.f - z) * nn + z * hp;
      }
    }
}

// ---------------- head v3: feat only (NO atomics)
__global__ __launch_bounds__(256) void head2_kernel(
    const float* __restrict__ hv, const float* __restrict__ x,
    const float* __restrict__ Wo1, const float* __restrict__ bo1,
    const float* __restrict__ Wo2, const float* __restrict__ bo2,
    float* __restrict__ feat) {
  __shared__ float wo1[64 * 64];
  __shared__ float wo2[64 * 64];
  __shared__ float s_row[NPB * 64];
  __shared__ float s_o1[NPB * 64];
  int tid = threadIdx.x;
  int n0 = blockIdx.x * NPB;

  for (int idx = tid; idx < 64 * 16; idx += 256) {
    ((float4*)wo1)[idx] = ((const float4*)Wo1)[idx];
    ((float4*)wo2)[idx] = ((const float4*)Wo2)[idx];
  }
  for (int idx = tid; idx < NPB * 64; idx += 256) {
    int n = n0 + (idx >> 6);
    s_row[idx] = (n < NN) ? hv[(size_t)n * 64 + (idx & 63)] : 0.f;
  }
  __syncthreads();

  int c = tid & 63, g = tid >> 6;
  #pragma unroll
  for (int q = 0; q < 8; ++q) {
    int nl = g + 4 * q;
    float a = bo1[c];
    for (int i = 0; i < 64; ++i) a = fmaf(s_row[nl * 64 + i], wo1[i * 64 + c], a);
    s_o1[nl * 64 + c] = fmaxf(a, 0.f);
  }
  __syncthreads();
  #pragma unroll
  for (int q = 0; q < 8; ++q) {
    int nl = g + 4 * q;
    int n = n0 + nl;
    float b = bo2[c];
    for (int i = 0; i < 64; ++i) b = fmaf(s_o1[nl * 64 + i], wo2[i * 64 + c], b);
    float xv = (c < NATOM && n < NN) ? x[(size_t)n * NATOM + c] : 0.f;
    float sq = b * b + xv * xv;
    #pragma unroll
    for (int off = 1; off < 64; off <<= 1) sq += __shfl_xor(sq, off);
    if (n >= NN) continue;
    float inv = 1.f / fmaxf(sqrtf(sq), 1e-12f);
    feat[(size_t)n * 90 + c] = b * inv;
    if (c < NATOM) feat[(size_t)n * 90 + 64 + c] = xv * inv;
  }
}

// ---------------- readout: segment mean prep via binary search (no atomics)
static __device__ __forceinline__ int lbound(const int* __restrict__ b, int v) {
  int lo = 0, hi = NN;
  while (lo < hi) { int m = (lo + hi) >> 1; if (b[m] < v) lo = m + 1; else hi = m; }
  return lo;
}

__global__ __launch_bounds__(128) void readout_kernel(
    const float* __restrict__ feat, const int* __restrict__ batch,
    float* __restrict__ readout, float* __restrict__ cnt) {
  __shared__ int bounds[2];
  int g = blockIdx.x;                // 0..63
  int t = threadIdx.x;
  if (t == 0) bounds[0] = lbound(batch, g);
  if (t == 1) bounds[1] = lbound(batch, g + 1);
  __syncthreads();
  int lo = bounds[0], hi = bounds[1];
  if (t < 90) {
    float a0 = 0.f, a1 = 0.f, a2 = 0.f, a3 = 0.f;
    int n = lo;
    for (; n + 3 < hi; n += 4) {
      a0 += feat[(size_t)n * 90 + t];
      a1 += feat[(size_t)(n + 1) * 90 + t];
      a2 += feat[(size_t)(n + 2) * 90 + t];
      a3 += feat[(size_t)(n + 3) * 90 + t];
    }
    for (; n < hi; ++n) a0 += feat[(size_t)n * 90 + t];
    readout[g * 90 + t] = (a0 + a1) + (a2 + a3);
  }
  if (t == 0) cnt[g] = (float)(hi - lo);
}

__global__ __launch_bounds__(64) void ratio_kernel(
    const float* __restrict__ readout, const float* __restrict__ cnt,
    const float* __restrict__ Wp, const float* __restrict__ bp,
    float* __restrict__ ratio) {
  int g = threadIdx.x;
  float c = fmaxf(cnt[g], 1.f);
  float a = bp[0];
  for (int j = 0; j < 90; ++j) a = fmaf(readout[g * 90 + j] / c, Wp[j], a);
  ratio[g] = 1.f / (1.f + __expf(-a));
}

// ==================== launcher ====================

extern "C" void kernel_launch(void* const* d_in, const int* in_sizes, int n_in,
                              void* d_out, int out_size, void* d_ws, size_t ws_size,
                              hipStream_t stream) {
  const float* x      = (const float*)d_in[0];
  const int*   ei     = (const int*)  d_in[1];
  const float* ea     = (const float*)d_in[2];
  const int*   batch  = (const int*)  d_in[3];
  const float* W_in   = (const float*)d_in[4];
  const float* b_in   = (const float*)d_in[5];
  const float* We1    = (const float*)d_in[6];
  const float* be1    = (const float*)d_in[7];
  const float* We2    = (const float*)d_in[8];
  const float* be2    = (const float*)d_in[9];
  const float* W_root = (const float*)d_in[10];
  const float* b_conv = (const float*)d_in[11];
  const float* W_ih   = (const float*)d_in[12];
  const float* b_ih   = (const float*)d_in[13];
  const float* W_hh   = (const float*)d_in[14];
  const float* b_hh   = (const float*)d_in[15];
  const float* Wo1    = (const float*)d_in[16];
  const float* bo1    = (const float*)d_in[17];
  const float* Wo2    = (const float*)d_in[18];
  const float* bo2    = (const float*)d_in[19];
  const float* Wp     = (const float*)d_in[20];
  const float* bp     = (const float*)d_in[21];

  const int* srcp = ei;
  const int* dstp = ei + NE;
  float* feat  = (float*)d_out;
  float* ratio = feat + (size_t)NN * 90;

  // ws layout (bytes): total ~27.2 MB (round-1 proved >= 39.3 MB available)
  char* wsb = (char*)d_ws;
  ushort* Upkt   = (ushort*)(wsb + 0);            // 13,246,464
  ushort* Bpk    = (ushort*)(wsb + 13246464);     //  1,081,344
  float*  h      = (float*) (wsb + 14327808);     //  6,400,000
  float*  agg    = (float*) (wsb + 20727808);     //  6,400,000
  float*  readout= (float*) (wsb + 27127808);     //     23,040
  float*  cnt    = (float*) (wsb + 27150848);     //        256
  ushort* Wr_pk  = (ushort*)(wsb + 27151104);     //      8,192
  ushort* Bih_pk = (ushort*)(wsb + 27159296);     //     24,576
  ushort* Bhh_pk = (ushort*)(wsb + 27183872);     //     24,576  -> 27,208,448 total

  edge_mlp_pack_kernel<<<NEP2 / 64, 256, 0, stream>>>(ea, We1, be1, Upkt);
  bpk_pack_kernel<<<(NCH * 8 * 4 * 64) / 256, 256, 0, stream>>>(We2, be2, Bpk);
  nw_pack_kernel<<<14, 256, 0, stream>>>(W_root, W_ih, W_hh, Wr_pk, Bih_pk, Bhh_pk);
  node_in_kernel<<<(NN * 64 + 255) / 256, 256, 0, stream>>>(x, W_in, b_in, h);

  for (int it = 0; it < NUM_ITER; ++it) {
    hipMemsetAsync(agg, 0, (size_t)NN * 64 * sizeof(float), stream);
    edge_rgemm6_kernel<<<dim3(NEP2 / EB2, 2, 2), 1024, 0, stream>>>(
        Upkt, Bpk, h, srcp, dstp, agg);
    node_update2_kernel<<<(NN + 127) / 128, 256, 0, stream>>>(
        h, agg, Wr_pk, Bih_pk, Bhh_pk, b_conv, b_ih, b_hh);
  }

  head2_kernel<<<(NN + NPB - 1) / NPB, 256, 0, stream>>>(
      h, x, Wo1, bo1, Wo2, bo2, feat);
  readout_kernel<<<64, 128, 0, stream>>>(feat, batch, readout, cnt);
  ratio_kernel<<<1, 64, 0, stream>>>(readout, cnt, Wp, bp, ratio);
}

// Round 13
// 427.081 us; speedup vs baseline: 2.3101x; 1.0989x over previous
//
#include <hip/hip_runtime.h>
#include <math.h>

#define NN 25000
#define NE 50000
#define NEP2 50176            // 112 * 448 edges (padded)
#define NATOM 26
#define NUM_ITER 3
#define NCH 33                // K' = 33 chunks x 256 (4 k-values x 64 i's)
#define NPB 32
#define EB3 448               // edges per block (14 waves x 32)
#define NWAVE 14
#define NTHR 896
#define KSP 17                // chunks per K-split block: [0,17) and [17,33)

typedef __attribute__((ext_vector_type(8))) short bf16x8;
typedef __attribute__((ext_vector_type(8))) unsigned short ushort8_t;
typedef __attribute__((ext_vector_type(4))) float f32x4;
union FragU { bf16x8 v; ushort4 q[2]; };

#define GLDS16(gp, lp) __builtin_amdgcn_global_load_lds( \
    (const __attribute__((address_space(1))) void*)(gp), \
    (__attribute__((address_space(3))) void*)(lp), 16, 0, 0)
#define GLDS4(gp, lp) __builtin_amdgcn_global_load_lds( \
    (const __attribute__((address_space(1))) void*)(gp), \
    (__attribute__((address_space(3))) void*)(lp), 4, 0, 0)

static __device__ __forceinline__ ushort f2bf(float f) {
  unsigned u = __float_as_uint(f);
  unsigned r = (u + 0x7FFFu + ((u >> 16) & 1u)) >> 16;
  return (ushort)r;
}
static __device__ __forceinline__ unsigned cvt_pk_bf16(float a, float b) {
  unsigned r;
  asm("v_cvt_pk_bf16_f32 %0, %1, %2" : "=v"(r) : "v"(a), "v"(b));
  return r;
}
static __device__ __forceinline__ float bflo(unsigned u) { return __uint_as_float(u << 16); }
static __device__ __forceinline__ float bfhi(unsigned u) { return __uint_as_float(u & 0xFFFF0000u); }

// ---------------- U pack: relu(ea@We1+be1) -> Upkt[g][e][4] bf16 (k-group-major)
__global__ __launch_bounds__(256) void edge_mlp_pack_kernel(
    const float* __restrict__ ea, const float* __restrict__ We1,
    const float* __restrict__ be1, ushort* __restrict__ Upkt) {
  int t = threadIdx.x;
  int el = t & 63, seg = t >> 6;
  int e = blockIdx.x * 64 + el;       // grid 784 -> e < 50176
  bool valid = (e < NE);
  float a0 = 0.f, a1 = 0.f, a2 = 0.f, a3 = 0.f;
  if (valid) { a0 = ea[e * 4]; a1 = ea[e * 4 + 1]; a2 = ea[e * 4 + 2]; a3 = ea[e * 4 + 3]; }
  #pragma unroll
  for (int q = 0; q < 8; ++q) {
    int g = seg * 8 + q;              // k-group 0..31 (k = 4g..4g+3 < 128)
    ushort out[4];
    #pragma unroll
    for (int kk = 0; kk < 4; ++kk) {
      int k = g * 4 + kk;
      float v = be1[k];
      v = fmaf(a0, We1[k], v);
      v = fmaf(a1, We1[128 + k], v);
      v = fmaf(a2, We1[256 + k], v);
      v = fmaf(a3, We1[384 + k], v);
      out[kk] = valid ? f2bf(fmaxf(v, 0.f)) : (ushort)0;
    }
    *(ushort4*)&Upkt[((size_t)g * NEP2 + e) * 4] = *(ushort4*)out;
  }
  if (seg == 0) {                     // g=32: k=128 -> 1.0 (be2 fold), 129..131 -> 0
    ushort out[4] = {(ushort)(valid ? 0x3F80 : 0), 0, 0, 0};
    *(ushort4*)&Upkt[((size_t)32 * NEP2 + e) * 4] = *(ushort4*)out;
  }
}

// ---------------- B pack: We2ext[f][o] -> per-lane fragment order
__global__ __launch_bounds__(256) void bpk_pack_kernel(
    const float* __restrict__ We2, const float* __restrict__ be2,
    ushort* __restrict__ Bpk) {
  int idx = blockIdx.x * 256 + threadIdx.x;   // 264 blocks -> 67584 = 33*8*4*64
  int lane = idx & 63;
  int nt = (idx >> 6) & 3;
  int ks = (idx >> 8) & 7;
  int c = idx >> 11;
  int l15 = lane & 15, lg = lane >> 4;
  int o = nt * 16 + l15;
  ushort v[8];
  #pragma unroll
  for (int j = 0; j < 8; ++j) {
    int kl = (j < 4) ? (4 * lg + j) : (12 + 4 * lg + j);   // split-halves k-map
    int f = c * 256 + ks * 32 + kl;
    int k = f >> 6, i = f & 63;
    float wv = 0.f;
    if (k < 128) wv = We2[(size_t)k * 4096 + i * 64 + o];
    else if (k == 128) wv = be2[i * 64 + o];
    v[j] = f2bf(wv);
  }
  *(ushort8_t*)(Bpk + (size_t)idx * 8) = *(ushort8_t*)v;
}

// ---------------- GRU/conv weight pack: fragment-linear bf16 in ws
__global__ __launch_bounds__(256) void nw_pack_kernel(
    const float* __restrict__ W_root, const float* __restrict__ W_ih,
    const float* __restrict__ W_hh, ushort* __restrict__ Wr_pk,
    ushort* __restrict__ Bih_pk, ushort* __restrict__ Bhh_pk) {
  int idx = blockIdx.x * 256 + threadIdx.x;   // 14 blocks -> 3584 frags
  if (idx >= 3584) return;
  int lane, nt, ks, kind;
  ushort* dstp;
  if (idx < 512)      { kind = 0; int f = idx;        lane = f & 63; nt = (f >> 6) % 4;  ks = (f >> 6) / 4;  dstp = Wr_pk  + (size_t)f * 8; }
  else if (idx < 2048){ kind = 1; int f = idx - 512;  lane = f & 63; nt = (f >> 6) % 12; ks = (f >> 6) / 12; dstp = Bih_pk + (size_t)f * 8; }
  else                { kind = 2; int f = idx - 2048; lane = f & 63; nt = (f >> 6) % 12; ks = (f >> 6) / 12; dstp = Bhh_pk + (size_t)f * 8; }
  int l15 = lane & 15, lg = lane >> 4;
  int col = nt * 16 + l15;
  ushort v[8];
  #pragma unroll
  for (int j = 0; j < 8; ++j) {
    int kl = (j < 4) ? (4 * lg + j) : (12 + 4 * lg + j);
    int i = ks * 32 + kl;
    float wv;
    if (kind == 0)      wv = W_root[i * 64 + col];
    else if (kind == 1) wv = W_ih[col * 64 + i];
    else                wv = W_hh[col * 64 + i];
    v[j] = f2bf(wv);
  }
  *(ushort8_t*)dstp = *(ushort8_t*)v;
}

// ---------------- fused edge-message GEMM v7: R10's verified body, 448-edge/14-wave
// blocks for 224-block grid (87.5% CU coverage). K split in 2. Wave tile 32 edges.
__global__ __launch_bounds__(NTHR, 1) void edge_rgemm7_kernel(
    const ushort* __restrict__ Upkt, const ushort* __restrict__ Bpk,
    const float* __restrict__ hv, const int* __restrict__ src,
    const int* __restrict__ dst, float* __restrict__ agg) {
  __shared__ ushort sB[2][16384];   // 2 x 32KB frag-packed B chunk (2048 frags x 8)
  __shared__ ushort sU[2][1792];    // 2 x 3.5KB U chunk [448 e][4 k]
  __shared__ ushort sS[448][72];    // 64.5KB: s bf16, padded row
  int tid = threadIdx.x;            // 0..895
  int lane = tid & 63, w = tid >> 6;  // 14 waves
  int l15 = lane & 15, lg = lane >> 4;
  int e0 = blockIdx.x * EB3;        // 112 edge-blocks
  int c0 = blockIdx.y * KSP;        // 0 or 17
  int c1 = (c0 + KSP < NCH) ? (c0 + KSP) : NCH;

  // issue chunk c0 staging via global_load_lds (linear layouts):
  // B: 32 wave-issues of 64 frags; wave w covers q = w, w+14, w+28 (<32)
  // U: 3584 B = 896 dwords; wave w covers dwords [w*64, w*64+64)
  {
    const ushort* bs = Bpk + (size_t)c0 * 16384;
    for (int q = w; q < 32; q += NWAVE)
      GLDS16(bs + ((size_t)(q * 64) + lane) * 8, &sB[0][(size_t)(q * 64) * 8]);
    const ushort* us = Upkt + ((size_t)c0 * NEP2 + e0) * 4;
    GLDS4((const char*)us + (size_t)(w * 64 + lane) * 4, (char*)&sU[0][0] + (size_t)w * 256);
  }

  // stage s = bf16(h[src[e]]) for 448 edges (overlaps the DMA): 7168 = 896*8
  #pragma unroll
  for (int r = 0; r < 8; ++r) {
    int idx = r * NTHR + tid;
    int el = idx >> 4, part = idx & 15;
    int e = e0 + el;
    float4 v = make_float4(0.f, 0.f, 0.f, 0.f);
    if (e < NE) v = ((const float4*)hv)[(size_t)src[e] * 16 + part];
    unsigned lo = cvt_pk_bf16(v.x, v.y);
    unsigned hi = cvt_pk_bf16(v.z, v.w);
    *(uint2*)&sS[el][part * 4] = make_uint2(lo, hi);
  }
  __syncthreads();   // drains glload (vmcnt) + sS writes (lgkm)

  // per-wave s fragments: row = w*32 + mt*16 + l15, i = p*32 + g*16 + 4*lg
  float4 sreg[2][2][2];
  #pragma unroll
  for (int mt = 0; mt < 2; ++mt)
    #pragma unroll
    for (int p = 0; p < 2; ++p)
      #pragma unroll
      for (int g = 0; g < 2; ++g) {
        uint2 d = *(const uint2*)&sS[w * 32 + mt * 16 + l15][p * 32 + g * 16 + 4 * lg];
        sreg[mt][p][g] = make_float4(bflo(d.x), bfhi(d.x), bflo(d.y), bfhi(d.y));
      }

  f32x4 acc[2][4];
  #pragma unroll
  for (int mt = 0; mt < 2; ++mt)
    #pragma unroll
    for (int nt = 0; nt < 4; ++nt) acc[mt][nt] = (f32x4){0.f, 0.f, 0.f, 0.f};

  for (int c = c0; c < c1; ++c) {
    int cur = (c - c0) & 1;
    bool more = (c + 1 < c1);
    if (more) {  // issue next-chunk DMA into the other buffer; in flight across compute
      int nb = cur ^ 1;
      const ushort* bs = Bpk + (size_t)(c + 1) * 16384;
      for (int q = w; q < 32; q += NWAVE)
        GLDS16(bs + ((size_t)(q * 64) + lane) * 8, &sB[nb][(size_t)(q * 64) * 8]);
      const ushort* us = Upkt + ((size_t)(c + 1) * NEP2 + e0) * 4;
      GLDS4((const char*)us + (size_t)(w * 64 + lane) * 4, (char*)&sU[nb][0] + (size_t)w * 256);
    }
    float uu[2][4];
    #pragma unroll
    for (int mt = 0; mt < 2; ++mt) {
      uint2 d = *(const uint2*)&sU[cur][(w * 32 + mt * 16 + l15) * 4];
      uu[mt][0] = bflo(d.x); uu[mt][1] = bfhi(d.x);
      uu[mt][2] = bflo(d.y); uu[mt][3] = bfhi(d.y);
    }
    #pragma unroll
    for (int ks = 0; ks < 8; ++ks) {
      int p = ks & 1, ku = ks >> 1;
      bf16x8 bfr[4];
      #pragma unroll
      for (int nt = 0; nt < 4; ++nt)
        bfr[nt] = *(const bf16x8*)&sB[cur][(((size_t)ks * 4 + nt) * 64 + lane) * 8];
      #pragma unroll
      for (int mt = 0; mt < 2; ++mt) {
        float u = uu[mt][ku];
        float4 s0 = sreg[mt][p][0], s1 = sreg[mt][p][1];
        union { bf16x8 v; unsigned u32[4]; } af;
        af.u32[0] = cvt_pk_bf16(s0.x * u, s0.y * u);
        af.u32[1] = cvt_pk_bf16(s0.z * u, s0.w * u);
        af.u32[2] = cvt_pk_bf16(s1.x * u, s1.y * u);
        af.u32[3] = cvt_pk_bf16(s1.z * u, s1.w * u);
        #pragma unroll
        for (int nt = 0; nt < 4; ++nt)
          acc[mt][nt] = __builtin_amdgcn_mfma_f32_16x16x32_bf16(af.v, bfr[nt], acc[mt][nt], 0, 0, 0);
      }
    }
    __syncthreads();  // drains next-chunk DMA (hidden under this chunk's compute)
  }

  // scatter: D row (within 16-tile) = lg*4 + rr, col = nt*16 + l15
  #pragma unroll
  for (int mt = 0; mt < 2; ++mt) {
    #pragma unroll
    for (int rr = 0; rr < 4; ++rr) {
      int e = e0 + w * 32 + mt * 16 + lg * 4 + rr;
      if (e < NE) {
        int d = dst[e];
        #pragma unroll
        for (int nt = 0; nt < 4; ++nt)
          atomicAdd(&agg[(size_t)d * 64 + nt * 16 + l15], acc[mt][nt][rr]);
      }
    }
  }
}

// ---------------- node input transform
__global__ __launch_bounds__(256) void node_in_kernel(
    const float* __restrict__ x, const float* __restrict__ W_in,
    const float* __restrict__ b_in, float* __restrict__ h) {
  int idx = blockIdx.x * 256 + threadIdx.x;
  if (idx >= NN * 64) return;
  int n = idx >> 6, c = idx & 63;
  float acc = b_in[c];
  #pragma unroll
  for (int j = 0; j < NATOM; ++j) acc = fmaf(x[n * NATOM + j], W_in[j * 64 + c], acc);
  h[idx] = fmaxf(acc, 0.f);
}

// ---------------- node update v2: MFMA GRU. 128 nodes/block, 256 thr (4 waves x 32 nodes)
__global__ __launch_bounds__(256, 1) void node_update2_kernel(
    float* __restrict__ hv, const float* __restrict__ agg,
    const ushort* __restrict__ Wr_pk, const ushort* __restrict__ Bih_pk,
    const ushort* __restrict__ Bhh_pk, const float* __restrict__ b_conv,
    const float* __restrict__ b_ih, const float* __restrict__ b_hh) {
  __shared__ ushort h_lds[128][72];   // 18 KB
  __shared__ ushort m_lds[128][72];   // 18 KB
  int tid = threadIdx.x;
  int lane = tid & 63, w = tid >> 6;
  int l15 = lane & 15, lg = lane >> 4;
  int n0 = blockIdx.x * 128;

  #pragma unroll
  for (int r = 0; r < 8; ++r) {
    int idx = r * 256 + tid;
    int row = idx >> 4, part = idx & 15;
    int n = n0 + row;
    float4 v = make_float4(0.f, 0.f, 0.f, 0.f);
    if (n < NN) v = ((const float4*)hv)[(size_t)n * 16 + part];
    *(uint2*)&h_lds[row][part * 4] =
        make_uint2(cvt_pk_bf16(v.x, v.y), cvt_pk_bf16(v.z, v.w));
  }
  __syncthreads();

  bf16x8 ah[2][2];
  #pragma unroll
  for (int mt = 0; mt < 2; ++mt)
    #pragma unroll
    for (int ks = 0; ks < 2; ++ks) {
      int row = w * 32 + mt * 16 + l15;
      FragU f;
      f.q[0] = *(const ushort4*)&h_lds[row][ks * 32 + 4 * lg];
      f.q[1] = *(const ushort4*)&h_lds[row][ks * 32 + 16 + 4 * lg];
      ah[mt][ks] = f.v;
    }

  f32x4 accm[2][4];
  #pragma unroll
  for (int mt = 0; mt < 2; ++mt)
    #pragma unroll
    for (int nt = 0; nt < 4; ++nt) accm[mt][nt] = (f32x4){0.f, 0.f, 0.f, 0.f};
  #pragma unroll
  for (int ks = 0; ks < 2; ++ks)
    #pragma unroll
    for (int nt = 0; nt < 4; ++nt) {
      bf16x8 b = *(const bf16x8*)(Wr_pk + ((size_t)((ks * 4 + nt) * 64 + lane)) * 8);
      #pragma unroll
      for (int mt = 0; mt < 2; ++mt)
        accm[mt][nt] = __builtin_amdgcn_mfma_f32_16x16x32_bf16(ah[mt][ks], b, accm[mt][nt], 0, 0, 0);
    }
  #pragma unroll
  for (int mt = 0; mt < 2; ++mt)
    #pragma unroll
    for (int nt = 0; nt < 4; ++nt) {
      int col = nt * 16 + l15;
      float bc = b_conv[col];
      #pragma unroll
      for (int rr = 0; rr < 4; ++rr) {
        int row = w * 32 + mt * 16 + lg * 4 + rr;
        int n = n0 + row;
        float val = 0.f;
        if (n < NN) val = fmaxf(accm[mt][nt][rr] + agg[(size_t)n * 64 + col] + bc, 0.f);
        m_lds[row][col] = f2bf(val);
      }
    }
  __syncthreads();

  bf16x8 am[2][2];
  #pragma unroll
  for (int mt = 0; mt < 2; ++mt)
    #pragma unroll
    for (int ks = 0; ks < 2; ++ks) {
      int row = w * 32 + mt * 16 + l15;
      FragU f;
      f.q[0] = *(const ushort4*)&m_lds[row][ks * 32 + 4 * lg];
      f.q[1] = *(const ushort4*)&m_lds[row][ks * 32 + 16 + 4 * lg];
      am[mt][ks] = f.v;
    }

  f32x4 acc_s[2][8], acc_in[2][4], acc_hn[2][4];
  #pragma unroll
  for (int mt = 0; mt < 2; ++mt) {
    #pragma unroll
    for (int nt = 0; nt < 8; ++nt) acc_s[mt][nt] = (f32x4){0.f, 0.f, 0.f, 0.f};
    #pragma unroll
    for (int nt = 0; nt < 4; ++nt) {
      acc_in[mt][nt] = (f32x4){0.f, 0.f, 0.f, 0.f};
      acc_hn[mt][nt] = (f32x4){0.f, 0.f, 0.f, 0.f};
    }
  }
  #pragma unroll
  for (int ks = 0; ks < 2; ++ks) {
    #pragma unroll
    for (int nt = 0; nt < 8; ++nt) {
      bf16x8 bi = *(const bf16x8*)(Bih_pk + ((size_t)((ks * 12 + nt) * 64 + lane)) * 8);
      bf16x8 bh = *(const bf16x8*)(Bhh_pk + ((size_t)((ks * 12 + nt) * 64 + lane)) * 8);
      #pragma unroll
      for (int mt = 0; mt < 2; ++mt) {
        acc_s[mt][nt] = __builtin_amdgcn_mfma_f32_16x16x32_bf16(am[mt][ks], bi, acc_s[mt][nt], 0, 0, 0);
        acc_s[mt][nt] = __builtin_amdgcn_mfma_f32_16x16x32_bf16(ah[mt][ks], bh, acc_s[mt][nt], 0, 0, 0);
      }
    }
    #pragma unroll
    for (int nt = 8; nt < 12; ++nt) {
      bf16x8 bi = *(const bf16x8*)(Bih_pk + ((size_t)((ks * 12 + nt) * 64 + lane)) * 8);
      bf16x8 bh = *(const bf16x8*)(Bhh_pk + ((size_t)((ks * 12 + nt) * 64 + lane)) * 8);
      #pragma unroll
      for (int mt = 0; mt < 2; ++mt) {
        acc_in[mt][nt - 8] = __builtin_amdgcn_mfma_f32_16x16x32_bf16(am[mt][ks], bi, acc_in[mt][nt - 8], 0, 0, 0);
        acc_hn[mt][nt - 8] = __builtin_amdgcn_mfma_f32_16x16x32_bf16(ah[mt][ks], bh, acc_hn[mt][nt - 8], 0, 0, 0);
      }
    }
  }

  #pragma unroll
  for (int mt = 0; mt < 2; ++mt)
    #pragma unroll
    for (int nt = 0; nt < 4; ++nt) {
      int col = nt * 16 + l15;
      float b_sr = b_ih[col] + b_hh[col];
      float b_sz = b_ih[64 + col] + b_hh[64 + col];
      float b_in_ = b_ih[128 + col];
      float b_hn = b_hh[128 + col];
      #pragma unroll
      for (int rr = 0; rr < 4; ++rr) {
        int row = w * 32 + mt * 16 + lg * 4 + rr;
        int n = n0 + row;
        if (n >= NN) continue;
        float Sr = acc_s[mt][nt][rr] + b_sr;
        float Sz = acc_s[mt][nt + 4][rr] + b_sz;
        float vin = acc_in[mt][nt][rr] + b_in_;
        float vhn = acc_hn[mt][nt][rr] + b_hn;
        float r = 1.f / (1.f + __expf(-Sr));
        float z = 1.f / (1.f + __expf(-Sz));
        float nn = tanhf(fmaf(r, vhn, vin));
        float hp = hv[(size_t)n * 64 + col];
        hv[(size_t)n * 64 + col] = (1.f - z) * nn + z * hp;
      }
    }
}

// ---------------- head v3: feat only (NO atomics)
__global__ __launch_bounds__(256) void head2_kernel(
    const float* __restrict__ hv, const float* __restrict__ x,
    const float* __restrict__ Wo1, const float* __restrict__ bo1,
    const float* __restrict__ Wo2, const float* __restrict__ bo2,
    float* __restrict__ feat) {
  __shared__ float wo1[64 * 64];
  __shared__ float wo2[64 * 64];
  __shared__ float s_row[NPB * 64];
  __shared__ float s_o1[NPB * 64];
  int tid = threadIdx.x;
  int n0 = blockIdx.x * NPB;

  for (int idx = tid; idx < 64 * 16; idx += 256) {
    ((float4*)wo1)[idx] = ((const float4*)Wo1)[idx];
    ((float4*)wo2)[idx] = ((const float4*)Wo2)[idx];
  }
  for (int idx = tid; idx < NPB * 64; idx += 256) {
    int n = n0 + (idx >> 6);
    s_row[idx] = (n < NN) ? hv[(size_t)n * 64 + (idx & 63)] : 0.f;
  }
  __syncthreads();

  int c = tid & 63, g = tid >> 6;
  #pragma unroll
  for (int q = 0; q < 8; ++q) {
    int nl = g + 4 * q;
    float a = bo1[c];
    for (int i = 0; i < 64; ++i) a = fmaf(s_row[nl * 64 + i], wo1[i * 64 + c], a);
    s_o1[nl * 64 + c] = fmaxf(a, 0.f);
  }
  __syncthreads();
  #pragma unroll
  for (int q = 0; q < 8; ++q) {
    int nl = g + 4 * q;
    int n = n0 + nl;
    float b = bo2[c];
    for (int i = 0; i < 64; ++i) b = fmaf(s_o1[nl * 64 + i], wo2[i * 64 + c], b);
    float xv = (c < NATOM && n < NN) ? x[(size_t)n * NATOM + c] : 0.f;
    float sq = b * b + xv * xv;
    #pragma unroll
    for (int off = 1; off < 64; off <<= 1) sq += __shfl_xor(sq, off);
    if (n >= NN) continue;
    float inv = 1.f / fmaxf(sqrtf(sq), 1e-12f);
    feat[(size_t)n * 90 + c] = b * inv;
    if (c < NATOM) feat[(size_t)n * 90 + 64 + c] = xv * inv;
  }
}

// ---------------- readout: segment mean prep via binary search (no atomics)
static __device__ __forceinline__ int lbound(const int* __restrict__ b, int v) {
  int lo = 0, hi = NN;
  while (lo < hi) { int m = (lo + hi) >> 1; if (b[m] < v) lo = m + 1; else hi = m; }
  return lo;
}

__global__ __launch_bounds__(128) void readout_kernel(
    const float* __restrict__ feat, const int* __restrict__ batch,
    float* __restrict__ readout, float* __restrict__ cnt) {
  __shared__ int bounds[2];
  int g = blockIdx.x;                // 0..63
  int t = threadIdx.x;
  if (t == 0) bounds[0] = lbound(batch, g);
  if (t == 1) bounds[1] = lbound(batch, g + 1);
  __syncthreads();
  int lo = bounds[0], hi = bounds[1];
  if (t < 90) {
    float a0 = 0.f, a1 = 0.f, a2 = 0.f, a3 = 0.f;
    int n = lo;
    for (; n + 3 < hi; n += 4) {
      a0 += feat[(size_t)n * 90 + t];
      a1 += feat[(size_t)(n + 1) * 90 + t];
      a2 += feat[(size_t)(n + 2) * 90 + t];
      a3 += feat[(size_t)(n + 3) * 90 + t];
    }
    for (; n < hi; ++n) a0 += feat[(size_t)n * 90 + t];
    readout[g * 90 + t] = (a0 + a1) + (a2 + a3);
  }
  if (t == 0) cnt[g] = (float)(hi - lo);
}

__global__ __launch_bounds__(64) void ratio_kernel(
    const float* __restrict__ readout, const float* __restrict__ cnt,
    const float* __restrict__ Wp, const float* __restrict__ bp,
    float* __restrict__ ratio) {
  int g = threadIdx.x;
  float c = fmaxf(cnt[g], 1.f);
  float a = bp[0];
  for (int j = 0; j < 90; ++j) a = fmaf(readout[g * 90 + j] / c, Wp[j], a);
  ratio[g] = 1.f / (1.f + __expf(-a));
}

// ==================== launcher ====================

extern "C" void kernel_launch(void* const* d_in, const int* in_sizes, int n_in,
                              void* d_out, int out_size, void* d_ws, size_t ws_size,
                              hipStream_t stream) {
  const float* x      = (const float*)d_in[0];
  const int*   ei     = (const int*)  d_in[1];
  const float* ea     = (const float*)d_in[2];
  const int*   batch  = (const int*)  d_in[3];
  const float* W_in   = (const float*)d_in[4];
  const float* b_in   = (const float*)d_in[5];
  const float* We1    = (const float*)d_in[6];
  const float* be1    = (const float*)d_in[7];
  const float* We2    = (const float*)d_in[8];
  const float* be2    = (const float*)d_in[9];
  const float* W_root = (const float*)d_in[10];
  const float* b_conv = (const float*)d_in[11];
  const float* W_ih   = (const float*)d_in[12];
  const float* b_ih   = (const float*)d_in[13];
  const float* W_hh   = (const float*)d_in[14];
  const float* b_hh   = (const float*)d_in[15];
  const float* Wo1    = (const float*)d_in[16];
  const float* bo1    = (const float*)d_in[17];
  const float* Wo2    = (const float*)d_in[18];
  const float* bo2    = (const float*)d_in[19];
  const float* Wp     = (const float*)d_in[20];
  const float* bp     = (const float*)d_in[21];

  const int* srcp = ei;
  const int* dstp = ei + NE;
  float* feat  = (float*)d_out;
  float* ratio = feat + (size_t)NN * 90;

  // ws layout (bytes): total ~27.2 MB (round-1 proved >= 39.3 MB available)
  char* wsb = (char*)d_ws;
  ushort* Upkt   = (ushort*)(wsb + 0);            // 13,246,464
  ushort* Bpk    = (ushort*)(wsb + 13246464);     //  1,081,344
  float*  h      = (float*) (wsb + 14327808);     //  6,400,000
  float*  agg    = (float*) (wsb + 20727808);     //  6,400,000
  float*  readout= (float*) (wsb + 27127808);     //     23,040
  float*  cnt    = (float*) (wsb + 27150848);     //        256
  ushort* Wr_pk  = (ushort*)(wsb + 27151104);     //      8,192
  ushort* Bih_pk = (ushort*)(wsb + 27159296);     //     24,576
  ushort* Bhh_pk = (ushort*)(wsb + 27183872);     //     24,576  -> 27,208,448 total

  edge_mlp_pack_kernel<<<NEP2 / 64, 256, 0, stream>>>(ea, We1, be1, Upkt);
  bpk_pack_kernel<<<(NCH * 8 * 4 * 64) / 256, 256, 0, stream>>>(We2, be2, Bpk);
  nw_pack_kernel<<<14, 256, 0, stream>>>(W_root, W_ih, W_hh, Wr_pk, Bih_pk, Bhh_pk);
  node_in_kernel<<<(NN * 64 + 255) / 256, 256, 0, stream>>>(x, W_in, b_in, h);

  for (int it = 0; it < NUM_ITER; ++it) {
    hipMemsetAsync(agg, 0, (size_t)NN * 64 * sizeof(float), stream);
    edge_rgemm7_kernel<<<dim3(NEP2 / EB3, 2), NTHR, 0, stream>>>(
        Upkt, Bpk, h, srcp, dstp, agg);
    node_update2_kernel<<<(NN + 127) / 128, 256, 0, stream>>>(
        h, agg, Wr_pk, Bih_pk, Bhh_pk, b_conv, b_ih, b_hh);
  }

  head2_kernel<<<(NN + NPB - 1) / NPB, 256, 0, stream>>>(
      h, x, Wo1, bo1, Wo2, bo2, feat);
  readout_kernel<<<64, 128, 0, stream>>>(feat, batch, readout, cnt);
  ratio_kernel<<<1, 64, 0, stream>>>(readout, cnt, Wp, bp, ratio);
}

// Round 14
// 400.177 us; speedup vs baseline: 2.4654x; 1.0672x over previous
//
#include <hip/hip_runtime.h>
#include <math.h>

#define NN 25000
#define NE 50000
#define NEP2 50176            // 112 * 448 edges (padded)
#define NATOM 26
#define NUM_ITER 3
#define NCH 33                // K' = 33 chunks x 256 (4 k-values x 64 i's)
#define NPB 32
#define EB3 448               // edges per block (14 waves x 32)
#define NWAVE 14
#define NTHR 896
#define KSP 17                // chunks per K-split block: [0,17) and [17,33)

typedef __attribute__((ext_vector_type(8))) short bf16x8;
typedef __attribute__((ext_vector_type(8))) unsigned short ushort8_t;
typedef __attribute__((ext_vector_type(4))) float f32x4;
union FragU { bf16x8 v; ushort4 q[2]; };

#define GLDS16(gp, lp) __builtin_amdgcn_global_load_lds( \
    (const __attribute__((address_space(1))) void*)(gp), \
    (__attribute__((address_space(3))) void*)(lp), 16, 0, 0)
#define GLDS4(gp, lp) __builtin_amdgcn_global_load_lds( \
    (const __attribute__((address_space(1))) void*)(gp), \
    (__attribute__((address_space(3))) void*)(lp), 4, 0, 0)

static __device__ __forceinline__ ushort f2bf(float f) {
  unsigned u = __float_as_uint(f);
  unsigned r = (u + 0x7FFFu + ((u >> 16) & 1u)) >> 16;
  return (ushort)r;
}
static __device__ __forceinline__ unsigned cvt_pk_bf16(float a, float b) {
  unsigned r;
  asm("v_cvt_pk_bf16_f32 %0, %1, %2" : "=v"(r) : "v"(a), "v"(b));
  return r;
}
static __device__ __forceinline__ float bflo(unsigned u) { return __uint_as_float(u << 16); }
static __device__ __forceinline__ float bfhi(unsigned u) { return __uint_as_float(u & 0xFFFF0000u); }

// ---------------- unified prep kernel (grid-sliced):
// blocks [0,784): U-pack | [784,1048): B-pack | [1048,1062): nw-pack
// [1062,1062+6250): node_in + agg zero
#define PB_U 784
#define PB_B (PB_U + 264)
#define PB_NW (PB_B + 14)
#define PB_NI (PB_NW + 6250)

__global__ __launch_bounds__(256) void prep_kernel(
    const float* __restrict__ ea, const float* __restrict__ We1,
    const float* __restrict__ be1, ushort* __restrict__ Upkt,
    const float* __restrict__ We2, const float* __restrict__ be2,
    ushort* __restrict__ Bpk,
    const float* __restrict__ W_root, const float* __restrict__ W_ih,
    const float* __restrict__ W_hh, ushort* __restrict__ Wr_pk,
    ushort* __restrict__ Bih_pk, ushort* __restrict__ Bhh_pk,
    const float* __restrict__ x, const float* __restrict__ W_in,
    const float* __restrict__ b_in, float* __restrict__ h,
    float* __restrict__ agg) {
  int b = blockIdx.x;
  int t = threadIdx.x;
  if (b < PB_U) {
    // ---- U pack: relu(ea@We1+be1) -> Upkt[g][e][4] bf16
    int el = t & 63, seg = t >> 6;
    int e = b * 64 + el;
    bool valid = (e < NE);
    float a0 = 0.f, a1 = 0.f, a2 = 0.f, a3 = 0.f;
    if (valid) { a0 = ea[e * 4]; a1 = ea[e * 4 + 1]; a2 = ea[e * 4 + 2]; a3 = ea[e * 4 + 3]; }
    #pragma unroll
    for (int q = 0; q < 8; ++q) {
      int g = seg * 8 + q;
      ushort out[4];
      #pragma unroll
      for (int kk = 0; kk < 4; ++kk) {
        int k = g * 4 + kk;
        float v = be1[k];
        v = fmaf(a0, We1[k], v);
        v = fmaf(a1, We1[128 + k], v);
        v = fmaf(a2, We1[256 + k], v);
        v = fmaf(a3, We1[384 + k], v);
        out[kk] = valid ? f2bf(fmaxf(v, 0.f)) : (ushort)0;
      }
      *(ushort4*)&Upkt[((size_t)g * NEP2 + e) * 4] = *(ushort4*)out;
    }
    if (seg == 0) {
      ushort out[4] = {(ushort)(valid ? 0x3F80 : 0), 0, 0, 0};
      *(ushort4*)&Upkt[((size_t)32 * NEP2 + e) * 4] = *(ushort4*)out;
    }
  } else if (b < PB_B) {
    // ---- B pack: We2ext[f][o] -> per-lane fragment order
    int idx = (b - PB_U) * 256 + t;
    int lane = idx & 63;
    int nt = (idx >> 6) & 3;
    int ks = (idx >> 8) & 7;
    int c = idx >> 11;
    int l15 = lane & 15, lg = lane >> 4;
    int o = nt * 16 + l15;
    ushort v[8];
    #pragma unroll
    for (int j = 0; j < 8; ++j) {
      int kl = (j < 4) ? (4 * lg + j) : (12 + 4 * lg + j);
      int f = c * 256 + ks * 32 + kl;
      int k = f >> 6, i = f & 63;
      float wv = 0.f;
      if (k < 128) wv = We2[(size_t)k * 4096 + i * 64 + o];
      else if (k == 128) wv = be2[i * 64 + o];
      v[j] = f2bf(wv);
    }
    *(ushort8_t*)(Bpk + (size_t)idx * 8) = *(ushort8_t*)v;
  } else if (b < PB_NW) {
    // ---- GRU/conv weight pack
    int idx = (b - PB_B) * 256 + t;
    if (idx >= 3584) return;
    int lane, nt, ks, kind;
    ushort* dstp;
    if (idx < 512)      { kind = 0; int f = idx;        lane = f & 63; nt = (f >> 6) % 4;  ks = (f >> 6) / 4;  dstp = Wr_pk  + (size_t)f * 8; }
    else if (idx < 2048){ kind = 1; int f = idx - 512;  lane = f & 63; nt = (f >> 6) % 12; ks = (f >> 6) / 12; dstp = Bih_pk + (size_t)f * 8; }
    else                { kind = 2; int f = idx - 2048; lane = f & 63; nt = (f >> 6) % 12; ks = (f >> 6) / 12; dstp = Bhh_pk + (size_t)f * 8; }
    int l15 = lane & 15, lg = lane >> 4;
    int col = nt * 16 + l15;
    ushort v[8];
    #pragma unroll
    for (int j = 0; j < 8; ++j) {
      int kl = (j < 4) ? (4 * lg + j) : (12 + 4 * lg + j);
      int i = ks * 32 + kl;
      float wv;
      if (kind == 0)      wv = W_root[i * 64 + col];
      else if (kind == 1) wv = W_ih[col * 64 + i];
      else                wv = W_hh[col * 64 + i];
      v[j] = f2bf(wv);
    }
    *(ushort8_t*)dstp = *(ushort8_t*)v;
  } else {
    // ---- node input transform + agg zero
    int idx = (b - PB_NW) * 256 + t;
    if (idx >= NN * 64) return;
    int n = idx >> 6, c = idx & 63;
    float acc = b_in[c];
    #pragma unroll
    for (int j = 0; j < NATOM; ++j) acc = fmaf(x[n * NATOM + j], W_in[j * 64 + c], acc);
    h[idx] = fmaxf(acc, 0.f);
    agg[idx] = 0.f;
  }
}

// ---------------- fused edge-message GEMM v7 (verified): 448 edges/14 waves, K-split 2
__global__ __launch_bounds__(NTHR, 1) void edge_rgemm7_kernel(
    const ushort* __restrict__ Upkt, const ushort* __restrict__ Bpk,
    const float* __restrict__ hv, const int* __restrict__ src,
    const int* __restrict__ dst, float* __restrict__ agg) {
  __shared__ ushort sB[2][16384];
  __shared__ ushort sU[2][1792];
  __shared__ ushort sS[448][72];
  int tid = threadIdx.x;
  int lane = tid & 63, w = tid >> 6;
  int l15 = lane & 15, lg = lane >> 4;
  int e0 = blockIdx.x * EB3;
  int c0 = blockIdx.y * KSP;
  int c1 = (c0 + KSP < NCH) ? (c0 + KSP) : NCH;

  {
    const ushort* bs = Bpk + (size_t)c0 * 16384;
    for (int q = w; q < 32; q += NWAVE)
      GLDS16(bs + ((size_t)(q * 64) + lane) * 8, &sB[0][(size_t)(q * 64) * 8]);
    const ushort* us = Upkt + ((size_t)c0 * NEP2 + e0) * 4;
    GLDS4((const char*)us + (size_t)(w * 64 + lane) * 4, (char*)&sU[0][0] + (size_t)w * 256);
  }

  #pragma unroll
  for (int r = 0; r < 8; ++r) {
    int idx = r * NTHR + tid;
    int el = idx >> 4, part = idx & 15;
    int e = e0 + el;
    float4 v = make_float4(0.f, 0.f, 0.f, 0.f);
    if (e < NE) v = ((const float4*)hv)[(size_t)src[e] * 16 + part];
    unsigned lo = cvt_pk_bf16(v.x, v.y);
    unsigned hi = cvt_pk_bf16(v.z, v.w);
    *(uint2*)&sS[el][part * 4] = make_uint2(lo, hi);
  }
  __syncthreads();

  float4 sreg[2][2][2];
  #pragma unroll
  for (int mt = 0; mt < 2; ++mt)
    #pragma unroll
    for (int p = 0; p < 2; ++p)
      #pragma unroll
      for (int g = 0; g < 2; ++g) {
        uint2 d = *(const uint2*)&sS[w * 32 + mt * 16 + l15][p * 32 + g * 16 + 4 * lg];
        sreg[mt][p][g] = make_float4(bflo(d.x), bfhi(d.x), bflo(d.y), bfhi(d.y));
      }

  f32x4 acc[2][4];
  #pragma unroll
  for (int mt = 0; mt < 2; ++mt)
    #pragma unroll
    for (int nt = 0; nt < 4; ++nt) acc[mt][nt] = (f32x4){0.f, 0.f, 0.f, 0.f};

  for (int c = c0; c < c1; ++c) {
    int cur = (c - c0) & 1;
    bool more = (c + 1 < c1);
    if (more) {
      int nb = cur ^ 1;
      const ushort* bs = Bpk + (size_t)(c + 1) * 16384;
      for (int q = w; q < 32; q += NWAVE)
        GLDS16(bs + ((size_t)(q * 64) + lane) * 8, &sB[nb][(size_t)(q * 64) * 8]);
      const ushort* us = Upkt + ((size_t)(c + 1) * NEP2 + e0) * 4;
      GLDS4((const char*)us + (size_t)(w * 64 + lane) * 4, (char*)&sU[nb][0] + (size_t)w * 256);
    }
    float uu[2][4];
    #pragma unroll
    for (int mt = 0; mt < 2; ++mt) {
      uint2 d = *(const uint2*)&sU[cur][(w * 32 + mt * 16 + l15) * 4];
      uu[mt][0] = bflo(d.x); uu[mt][1] = bfhi(d.x);
      uu[mt][2] = bflo(d.y); uu[mt][3] = bfhi(d.y);
    }
    #pragma unroll
    for (int ks = 0; ks < 8; ++ks) {
      int p = ks & 1, ku = ks >> 1;
      bf16x8 bfr[4];
      #pragma unroll
      for (int nt = 0; nt < 4; ++nt)
        bfr[nt] = *(const bf16x8*)&sB[cur][(((size_t)ks * 4 + nt) * 64 + lane) * 8];
      #pragma unroll
      for (int mt = 0; mt < 2; ++mt) {
        float u = uu[mt][ku];
        float4 s0 = sreg[mt][p][0], s1 = sreg[mt][p][1];
        union { bf16x8 v; unsigned u32[4]; } af;
        af.u32[0] = cvt_pk_bf16(s0.x * u, s0.y * u);
        af.u32[1] = cvt_pk_bf16(s0.z * u, s0.w * u);
        af.u32[2] = cvt_pk_bf16(s1.x * u, s1.y * u);
        af.u32[3] = cvt_pk_bf16(s1.z * u, s1.w * u);
        #pragma unroll
        for (int nt = 0; nt < 4; ++nt)
          acc[mt][nt] = __builtin_amdgcn_mfma_f32_16x16x32_bf16(af.v, bfr[nt], acc[mt][nt], 0, 0, 0);
      }
    }
    __syncthreads();
  }

  #pragma unroll
  for (int mt = 0; mt < 2; ++mt) {
    #pragma unroll
    for (int rr = 0; rr < 4; ++rr) {
      int e = e0 + w * 32 + mt * 16 + lg * 4 + rr;
      if (e < NE) {
        int d = dst[e];
        #pragma unroll
        for (int nt = 0; nt < 4; ++nt)
          atomicAdd(&agg[(size_t)d * 64 + nt * 16 + l15], acc[mt][nt][rr]);
      }
    }
  }
}

// ---------------- node update v2 (verified) + agg re-zero for next iteration
__global__ __launch_bounds__(256, 1) void node_update2_kernel(
    float* __restrict__ hv, float* __restrict__ agg,
    const ushort* __restrict__ Wr_pk, const ushort* __restrict__ Bih_pk,
    const ushort* __restrict__ Bhh_pk, const float* __restrict__ b_conv,
    const float* __restrict__ b_ih, const float* __restrict__ b_hh) {
  __shared__ ushort h_lds[128][72];
  __shared__ ushort m_lds[128][72];
  int tid = threadIdx.x;
  int lane = tid & 63, w = tid >> 6;
  int l15 = lane & 15, lg = lane >> 4;
  int n0 = blockIdx.x * 128;

  #pragma unroll
  for (int r = 0; r < 8; ++r) {
    int idx = r * 256 + tid;
    int row = idx >> 4, part = idx & 15;
    int n = n0 + row;
    float4 v = make_float4(0.f, 0.f, 0.f, 0.f);
    if (n < NN) v = ((const float4*)hv)[(size_t)n * 16 + part];
    *(uint2*)&h_lds[row][part * 4] =
        make_uint2(cvt_pk_bf16(v.x, v.y), cvt_pk_bf16(v.z, v.w));
  }
  __syncthreads();

  bf16x8 ah[2][2];
  #pragma unroll
  for (int mt = 0; mt < 2; ++mt)
    #pragma unroll
    for (int ks = 0; ks < 2; ++ks) {
      int row = w * 32 + mt * 16 + l15;
      FragU f;
      f.q[0] = *(const ushort4*)&h_lds[row][ks * 32 + 4 * lg];
      f.q[1] = *(const ushort4*)&h_lds[row][ks * 32 + 16 + 4 * lg];
      ah[mt][ks] = f.v;
    }

  f32x4 accm[2][4];
  #pragma unroll
  for (int mt = 0; mt < 2; ++mt)
    #pragma unroll
    for (int nt = 0; nt < 4; ++nt) accm[mt][nt] = (f32x4){0.f, 0.f, 0.f, 0.f};
  #pragma unroll
  for (int ks = 0; ks < 2; ++ks)
    #pragma unroll
    for (int nt = 0; nt < 4; ++nt) {
      bf16x8 b = *(const bf16x8*)(Wr_pk + ((size_t)((ks * 4 + nt) * 64 + lane)) * 8);
      #pragma unroll
      for (int mt = 0; mt < 2; ++mt)
        accm[mt][nt] = __builtin_amdgcn_mfma_f32_16x16x32_bf16(ah[mt][ks], b, accm[mt][nt], 0, 0, 0);
    }
  #pragma unroll
  for (int mt = 0; mt < 2; ++mt)
    #pragma unroll
    for (int nt = 0; nt < 4; ++nt) {
      int col = nt * 16 + l15;
      float bc = b_conv[col];
      #pragma unroll
      for (int rr = 0; rr < 4; ++rr) {
        int row = w * 32 + mt * 16 + lg * 4 + rr;
        int n = n0 + row;
        float val = 0.f;
        if (n < NN) {
          val = fmaxf(accm[mt][nt][rr] + agg[(size_t)n * 64 + col] + bc, 0.f);
          agg[(size_t)n * 64 + col] = 0.f;   // re-zero for next iteration
        }
        m_lds[row][col] = f2bf(val);
      }
    }
  __syncthreads();

  bf16x8 am[2][2];
  #pragma unroll
  for (int mt = 0; mt < 2; ++mt)
    #pragma unroll
    for (int ks = 0; ks < 2; ++ks) {
      int row = w * 32 + mt * 16 + l15;
      FragU f;
      f.q[0] = *(const ushort4*)&m_lds[row][ks * 32 + 4 * lg];
      f.q[1] = *(const ushort4*)&m_lds[row][ks * 32 + 16 + 4 * lg];
      am[mt][ks] = f.v;
    }

  f32x4 acc_s[2][8], acc_in[2][4], acc_hn[2][4];
  #pragma unroll
  for (int mt = 0; mt < 2; ++mt) {
    #pragma unroll
    for (int nt = 0; nt < 8; ++nt) acc_s[mt][nt] = (f32x4){0.f, 0.f, 0.f, 0.f};
    #pragma unroll
    for (int nt = 0; nt < 4; ++nt) {
      acc_in[mt][nt] = (f32x4){0.f, 0.f, 0.f, 0.f};
      acc_hn[mt][nt] = (f32x4){0.f, 0.f, 0.f, 0.f};
    }
  }
  #pragma unroll
  for (int ks = 0; ks < 2; ++ks) {
    #pragma unroll
    for (int nt = 0; nt < 8; ++nt) {
      bf16x8 bi = *(const bf16x8*)(Bih_pk + ((size_t)((ks * 12 + nt) * 64 + lane)) * 8);
      bf16x8 bh = *(const bf16x8*)(Bhh_pk + ((size_t)((ks * 12 + nt) * 64 + lane)) * 8);
      #pragma unroll
      for (int mt = 0; mt < 2; ++mt) {
        acc_s[mt][nt] = __builtin_amdgcn_mfma_f32_16x16x32_bf16(am[mt][ks], bi, acc_s[mt][nt], 0, 0, 0);
        acc_s[mt][nt] = __builtin_amdgcn_mfma_f32_16x16x32_bf16(ah[mt][ks], bh, acc_s[mt][nt], 0, 0, 0);
      }
    }
    #pragma unroll
    for (int nt = 8; nt < 12; ++nt) {
      bf16x8 bi = *(const bf16x8*)(Bih_pk + ((size_t)((ks * 12 + nt) * 64 + lane)) * 8);
      bf16x8 bh = *(const bf16x8*)(Bhh_pk + ((size_t)((ks * 12 + nt) * 64 + lane)) * 8);
      #pragma unroll
      for (int mt = 0; mt < 2; ++mt) {
        acc_in[mt][nt - 8] = __builtin_amdgcn_mfma_f32_16x16x32_bf16(am[mt][ks], bi, acc_in[mt][nt - 8], 0, 0, 0);
        acc_hn[mt][nt - 8] = __builtin_amdgcn_mfma_f32_16x16x32_bf16(ah[mt][ks], bh, acc_hn[mt][nt - 8], 0, 0, 0);
      }
    }
  }

  #pragma unroll
  for (int mt = 0; mt < 2; ++mt)
    #pragma unroll
    for (int nt = 0; nt < 4; ++nt) {
      int col = nt * 16 + l15;
      float b_sr = b_ih[col] + b_hh[col];
      float b_sz = b_ih[64 + col] + b_hh[64 + col];
      float b_in_ = b_ih[128 + col];
      float b_hn = b_hh[128 + col];
      #pragma unroll
      for (int rr = 0; rr < 4; ++rr) {
        int row = w * 32 + mt * 16 + lg * 4 + rr;
        int n = n0 + row;
        if (n >= NN) continue;
        float Sr = acc_s[mt][nt][rr] + b_sr;
        float Sz = acc_s[mt][nt + 4][rr] + b_sz;
        float vin = acc_in[mt][nt][rr] + b_in_;
        float vhn = acc_hn[mt][nt][rr] + b_hn;
        float r = 1.f / (1.f + __expf(-Sr));
        float z = 1.f / (1.f + __expf(-Sz));
        float nn = tanhf(fmaf(r, vhn, vin));
        float hp = hv[(size_t)n * 64 + col];
        hv[(size_t)n * 64 + col] = (1.f - z) * nn + z * hp;
      }
    }
}

// ---------------- head v3: feat only (NO atomics)
__global__ __launch_bounds__(256) void head2_kernel(
    const float* __restrict__ hv, const float* __restrict__ x,
    const float* __restrict__ Wo1, const float* __restrict__ bo1,
    const float* __restrict__ Wo2, const float* __restrict__ bo2,
    float* __restrict__ feat) {
  __shared__ float wo1[64 * 64];
  __shared__ float wo2[64 * 64];
  __shared__ float s_row[NPB * 64];
  __shared__ float s_o1[NPB * 64];
  int tid = threadIdx.x;
  int n0 = blockIdx.x * NPB;

  for (int idx = tid; idx < 64 * 16; idx += 256) {
    ((float4*)wo1)[idx] = ((const float4*)Wo1)[idx];
    ((float4*)wo2)[idx] = ((const float4*)Wo2)[idx];
  }
  for (int idx = tid; idx < NPB * 64; idx += 256) {
    int n = n0 + (idx >> 6);
    s_row[idx] = (n < NN) ? hv[(size_t)n * 64 + (idx & 63)] : 0.f;
  }
  __syncthreads();

  int c = tid & 63, g = tid >> 6;
  #pragma unroll
  for (int q = 0; q < 8; ++q) {
    int nl = g + 4 * q;
    float a = bo1[c];
    for (int i = 0; i < 64; ++i) a = fmaf(s_row[nl * 64 + i], wo1[i * 64 + c], a);
    s_o1[nl * 64 + c] = fmaxf(a, 0.f);
  }
  __syncthreads();
  #pragma unroll
  for (int q = 0; q < 8; ++q) {
    int nl = g + 4 * q;
    int n = n0 + nl;
    float b = bo2[c];
    for (int i = 0; i < 64; ++i) b = fmaf(s_o1[nl * 64 + i], wo2[i * 64 + c], b);
    float xv = (c < NATOM && n < NN) ? x[(size_t)n * NATOM + c] : 0.f;
    float sq = b * b + xv * xv;
    #pragma unroll
    for (int off = 1; off < 64; off <<= 1) sq += __shfl_xor(sq, off);
    if (n >= NN) continue;
    float inv = 1.f / fmaxf(sqrtf(sq), 1e-12f);
    feat[(size_t)n * 90 + c] = b * inv;
    if (c < NATOM) feat[(size_t)n * 90 + 64 + c] = xv * inv;
  }
}

// ---------------- fused readout + ratio (block-local per graph; no ws, no atomics)
static __device__ __forceinline__ int lbound(const int* __restrict__ b, int v) {
  int lo = 0, hi = NN;
  while (lo < hi) { int m = (lo + hi) >> 1; if (b[m] < v) lo = m + 1; else hi = m; }
  return lo;
}

__global__ __launch_bounds__(128) void readout_ratio_kernel(
    const float* __restrict__ feat, const int* __restrict__ batch,
    const float* __restrict__ Wp, const float* __restrict__ bp,
    float* __restrict__ ratio) {
  __shared__ int bounds[2];
  __shared__ float sred[128];
  int g = blockIdx.x;                // 0..63
  int t = threadIdx.x;
  if (t == 0) bounds[0] = lbound(batch, g);
  if (t == 1) bounds[1] = lbound(batch, g + 1);
  __syncthreads();
  int lo = bounds[0], hi = bounds[1];
  float sum = 0.f;
  if (t < 90) {
    float a0 = 0.f, a1 = 0.f, a2 = 0.f, a3 = 0.f;
    int n = lo;
    for (; n + 3 < hi; n += 4) {
      a0 += feat[(size_t)n * 90 + t];
      a1 += feat[(size_t)(n + 1) * 90 + t];
      a2 += feat[(size_t)(n + 2) * 90 + t];
      a3 += feat[(size_t)(n + 3) * 90 + t];
    }
    for (; n < hi; ++n) a0 += feat[(size_t)n * 90 + t];
    sum = (a0 + a1) + (a2 + a3);
  }
  sred[t] = (t < 90) ? sum * Wp[t] : 0.f;
  __syncthreads();
  #pragma unroll
  for (int s = 64; s > 0; s >>= 1) {
    if (t < s) sred[t] += sred[t + s];
    __syncthreads();
  }
  if (t == 0) {
    float c = fmaxf((float)(hi - lo), 1.f);
    float a = sred[0] / c + bp[0];
    ratio[g] = 1.f / (1.f + __expf(-a));
  }
}

// ==================== launcher ====================

extern "C" void kernel_launch(void* const* d_in, const int* in_sizes, int n_in,
                              void* d_out, int out_size, void* d_ws, size_t ws_size,
                              hipStream_t stream) {
  const float* x      = (const float*)d_in[0];
  const int*   ei     = (const int*)  d_in[1];
  const float* ea     = (const float*)d_in[2];
  const int*   batch  = (const int*)  d_in[3];
  const float* W_in   = (const float*)d_in[4];
  const float* b_in   = (const float*)d_in[5];
  const float* We1    = (const float*)d_in[6];
  const float* be1    = (const float*)d_in[7];
  const float* We2    = (const float*)d_in[8];
  const float* be2    = (const float*)d_in[9];
  const float* W_root = (const float*)d_in[10];
  const float* b_conv = (const float*)d_in[11];
  const float* W_ih   = (const float*)d_in[12];
  const float* b_ih   = (const float*)d_in[13];
  const float* W_hh   = (const float*)d_in[14];
  const float* b_hh   = (const float*)d_in[15];
  const float* Wo1    = (const float*)d_in[16];
  const float* bo1    = (const float*)d_in[17];
  const float* Wo2    = (const float*)d_in[18];
  const float* bo2    = (const float*)d_in[19];
  const float* Wp     = (const float*)d_in[20];
  const float* bp     = (const float*)d_in[21];

  const int* srcp = ei;
  const int* dstp = ei + NE;
  float* feat  = (float*)d_out;
  float* ratio = feat + (size_t)NN * 90;

  // ws layout (bytes): total ~27.2 MB
  char* wsb = (char*)d_ws;
  ushort* Upkt   = (ushort*)(wsb + 0);            // 13,246,464
  ushort* Bpk    = (ushort*)(wsb + 13246464);     //  1,081,344
  float*  h      = (float*) (wsb + 14327808);     //  6,400,000
  float*  agg    = (float*) (wsb + 20727808);     //  6,400,000
  ushort* Wr_pk  = (ushort*)(wsb + 27151104);     //      8,192
  ushort* Bih_pk = (ushort*)(wsb + 27159296);     //     24,576
  ushort* Bhh_pk = (ushort*)(wsb + 27183872);     //     24,576

  prep_kernel<<<PB_NI, 256, 0, stream>>>(
      ea, We1, be1, Upkt, We2, be2, Bpk,
      W_root, W_ih, W_hh, Wr_pk, Bih_pk, Bhh_pk,
      x, W_in, b_in, h, agg);

  for (int it = 0; it < NUM_ITER; ++it) {
    edge_rgemm7_kernel<<<dim3(NEP2 / EB3, 2), NTHR, 0, stream>>>(
        Upkt, Bpk, h, srcp, dstp, agg);
    node_update2_kernel<<<(NN + 127) / 128, 256, 0, stream>>>(
        h, agg, Wr_pk, Bih_pk, Bhh_pk, b_conv, b_ih, b_hh);
  }

  head2_kernel<<<(NN + NPB - 1) / NPB, 256, 0, stream>>>(
      h, x, Wo1, bo1, Wo2, bo2, feat);
  readout_ratio_kernel<<<64, 128, 0, stream>>>(feat, batch, Wp, bp, ratio);
}